// Round 5
// baseline (553.048 us; speedup 1.0000x reference)
//
#include <hip/hip_runtime.h>

typedef __attribute__((ext_vector_type(8))) short short8;
typedef __attribute__((ext_vector_type(4))) float f32x4;

#define DEV static __device__ __forceinline__

DEV float bfs2f(short s) {
    union { unsigned int u; float f; } c;
    c.u = ((unsigned int)(unsigned short)s) << 16;
    return c.f;
}
DEV short f2bfs(float f) {
    union { float f; unsigned int u; } c;
    c.f = f;
    unsigned int u = c.u;
    return (short)((u + 0x7fffu + ((u >> 16) & 1u)) >> 16);  // RNE
}
DEV int imin(int a, int b) { return a < b ? a : b; }
DEV float sigm(float x) { return 1.f / (1.f + expf(-x)); }

// ---------------------------------------------------------------------------
// Fused f32->bf16 convert of all plain weights + zero of M1f (one launch).
// ---------------------------------------------------------------------------
__global__ __launch_bounds__(256) void cvt_all_k(
    const float* __restrict__ Wq, const float* __restrict__ Wk, const float* __restrict__ Wv,
    const float* __restrict__ gih, const float* __restrict__ ghh, const float* __restrict__ cv,
    short* __restrict__ dWq, short* __restrict__ dWk, short* __restrict__ dWv,
    short* __restrict__ dgih, short* __restrict__ dghh, short* __restrict__ dcv,
    float* __restrict__ M1f)
{
    long i = (long)blockIdx.x * 256 + threadIdx.x;
    const float* s; short* d; long o;
    if      (i < 4194304) { s = Wq;  d = dWq;  o = i; }
    else if (i < 4718592) { s = Wk;  d = dWk;  o = i - 4194304; }
    else if (i < 5242880) { s = Wv;  d = dWv;  o = i - 4718592; }
    else if (i < 6029312) { s = gih; d = dgih; o = i - 5242880; }
    else if (i < 6815744) { s = ghh; d = dghh; o = i - 6029312; }
    else if (i < 6946816) { s = cv;  d = dcv;  o = i - 6815744; }
    else if (i < 7471104) { M1f[i - 6946816] = 0.f; return; }
    else return;
    d[o] = f2bfs(s[o]);
}

// ---------------------------------------------------------------------------
// All weight transposes (f32 [R,C] -> bf16 [C,R]) in ONE launch.
// ---------------------------------------------------------------------------
__global__ __launch_bounds__(256) void transpose_all_k(
    const float* __restrict__ mW1, const float* __restrict__ mW2,
    const float* __restrict__ cW1, const float* __restrict__ cW2,
    const float* __restrict__ cW3, const float* __restrict__ cW4,
    short* __restrict__ mW1T, short* __restrict__ mW2T,
    short* __restrict__ cW1T, short* __restrict__ cW2T,
    short* __restrict__ cW3T, short* __restrict__ cW4T)
{
    int id = blockIdx.x;
    const float* in; short* out; int R, C, tx, ty;
    if (id < 256)       { int z = id >> 4, t = id & 15; in = mW1 + z * 16384; out = mW1T + z * 16384; R = 128; C = 128; tx = t & 3;  ty = t >> 2; }
    else if (id < 512)  { id -= 256; int z = id >> 4, t = id & 15; in = mW2 + z * 16384; out = mW2T + z * 16384; R = 128; C = 128; tx = t & 3;  ty = t >> 2; }
    else if (id < 576)  { id -= 512;  in = cW1; out = cW1T; R = 128; C = 512; tx = id & 15; ty = id >> 4; }
    else if (id < 832)  { id -= 576;  in = cW2; out = cW2T; R = 512; C = 512; tx = id & 15; ty = id >> 4; }
    else if (id < 1088) { id -= 832;  in = cW3; out = cW3T; R = 512; C = 512; tx = id & 15; ty = id >> 4; }
    else                { id -= 1088; in = cW4; out = cW4T; R = 512; C = 128; tx = id & 3;  ty = id >> 2; }
    __shared__ short t[32][33];
    int c0 = tx * 32, r0 = ty * 32;
    int x = threadIdx.x & 31, y = threadIdx.x >> 5;
    #pragma unroll
    for (int k = 0; k < 32; k += 8) t[y + k][x] = f2bfs(in[(long)(r0 + y + k) * C + (c0 + x)]);
    __syncthreads();
    #pragma unroll
    for (int k = 0; k < 32; k += 8) out[(long)(c0 + y + k) * R + (r0 + x)] = t[x][y + k];
}

// bf16 transpose per b: xbf [b,1024,256] -> xbfT [b,256,1024]
__global__ __launch_bounds__(256) void xt_k(const short* __restrict__ in,
                                            short* __restrict__ out)
{
    int b = blockIdx.z;
    int i0 = blockIdx.x * 32, n0 = blockIdx.y * 32;
    __shared__ short tl[32][33];
    int x = threadIdx.x & 31, y = threadIdx.x >> 5;
    const short* ip = in + (long)b * 262144;
    short* op = out + (long)b * 262144;
    #pragma unroll
    for (int k = 0; k < 32; k += 8) tl[y + k][x] = ip[(long)(n0 + y + k) * 256 + i0 + x];
    __syncthreads();
    #pragma unroll
    for (int k = 0; k < 32; k += 8) op[(long)(i0 + y + k) * 1024 + n0 + x] = tl[x][y + k];
}

// ---------------------------------------------------------------------------
// Merged folded-bias prep: c1 and b1g
// ---------------------------------------------------------------------------
__global__ __launch_bounds__(256) void b1c1_k(const float* __restrict__ bq,
                                              const float* __restrict__ Wk,
                                              const float* __restrict__ bv,
                                              const float* __restrict__ gWih,
                                              float* __restrict__ c1,
                                              float* __restrict__ b1g)
{
    int bid = blockIdx.x, tid = threadIdx.x;
    __shared__ float red[4];
    if (bid < 256) {
        const float* row = Wk + (long)bid * 2048;
        float acc = 0.f;
        for (int d = tid; d < 2048; d += 256) acc += bq[d] * row[d];
        #pragma unroll
        for (int d = 1; d < 64; d <<= 1) acc += __shfl_xor(acc, d);
        int w = tid >> 6;
        if ((tid & 63) == 0) red[w] = acc;
        __syncthreads();
        if (tid == 0) c1[bid] = red[0] + red[1] + red[2] + red[3];
    } else {
        int t = (bid - 256) * 256 + tid;   // < 6144
        int nb = t / 384, g = t % 384;
        const float* wrow = gWih + (long)nb * 49152 + (long)g * 128;
        const float* bp = bv + nb * 128;
        float acc = 0.f;
        for (int j = 0; j < 128; j++) acc += bp[j] * wrow[j];
        b1g[t] = acc;
    }
}

// M1f (f32, 524288) -> M1bf (bf16)
__global__ __launch_bounds__(256) void cvt_m1_k(const float* __restrict__ in,
                                                short* __restrict__ out)
{
    int i = (blockIdx.x * 256 + threadIdx.x) * 4;
    f32x4 v = *(const f32x4*)(in + i);
    out[i]     = f2bfs(v[0]);
    out[i + 1] = f2bfs(v[1]);
    out[i + 2] = f2bfs(v[2]);
    out[i + 3] = f2bfs(v[3]);
}

// ---------------------------------------------------------------------------
// Tiled MFMA GEMM (unchanged from verified r3 version).
// ---------------------------------------------------------------------------
template<int OUT_MODE, int RELU, int HAS_BIAS, int A_F32, int B_F32, int SPLITK>
__global__ __launch_bounds__(256) void gemm_bt(
    const void* __restrict__ Av, long lda, long aoff,
    const void* __restrict__ Btv, long ldb, long boff,
    void* __restrict__ Cv, long ldc, long coff,
    const float* __restrict__ bias, long biasoff,
    int M, int N, int K, float scale)
{
    const int bz = blockIdx.z;
    long abase, bbase, cbase;
    int kbeg, kend, addbias;
    if (SPLITK > 1) {
        int ks = K / SPLITK;
        kbeg = bz * ks; kend = kbeg + ks;
        abase = 0; bbase = 0; cbase = 0; addbias = (bz == 0);
    } else {
        kbeg = 0; kend = K;
        abase = (long)bz * aoff; bbase = (long)bz * boff; cbase = (long)bz * coff;
        addbias = 1;
    }
    const int tid  = threadIdx.x;
    const int wave = tid >> 6, lane = tid & 63;
    const int quad = lane >> 4, l16 = lane & 15;
    const int wr = (wave >> 1) * 32, wc = (wave & 1) * 32;
    const int m0 = blockIdx.x * 64, n0 = blockIdx.y * 64;

    __shared__ __align__(16) short As[64 * 40];
    __shared__ __align__(16) short Bs[64 * 40];

    f32x4 acc[2][2] = {};

    const int lrow = tid >> 2;
    const int lk   = (tid & 3) * 8;
    const int arow = imin(m0 + lrow, M - 1);
    const int brow = imin(n0 + lrow, N - 1);
    short* asd = &As[lrow * 40 + lk];
    short* bsd = &Bs[lrow * 40 + lk];

    short8 arS = {}, brS = {};
    f32x4 arF0 = {}, arF1 = {}, brF0 = {}, brF1 = {};

    auto loadA = [&](int k0) {
        if (A_F32) {
            const float* p = (const float*)Av + abase + (long)arow * lda + lk + k0;
            arF0 = *(const f32x4*)p; arF1 = *(const f32x4*)(p + 4);
        } else {
            arS = *(const short8*)((const short*)Av + abase + (long)arow * lda + lk + k0);
        }
    };
    auto loadB = [&](int k0) {
        if (B_F32) {
            const float* p = (const float*)Btv + bbase + (long)brow * ldb + lk + k0;
            brF0 = *(const f32x4*)p; brF1 = *(const f32x4*)(p + 4);
        } else {
            brS = *(const short8*)((const short*)Btv + bbase + (long)brow * ldb + lk + k0);
        }
    };
    auto stage = [&]() {
        if (A_F32) {
            short8 t;
            #pragma unroll
            for (int j = 0; j < 4; j++) { t[j] = f2bfs(arF0[j]); t[j + 4] = f2bfs(arF1[j]); }
            *(short8*)asd = t;
        } else *(short8*)asd = arS;
        if (B_F32) {
            short8 t;
            #pragma unroll
            for (int j = 0; j < 4; j++) { t[j] = f2bfs(brF0[j]); t[j + 4] = f2bfs(brF1[j]); }
            *(short8*)bsd = t;
        } else *(short8*)bsd = brS;
    };

    loadA(kbeg); loadB(kbeg);
    for (int k0 = kbeg; k0 < kend; k0 += 32) {
        stage();
        __syncthreads();
        if (k0 + 32 < kend) { loadA(k0 + 32); loadB(k0 + 32); }
        short8 a0 = *(const short8*)&As[(wr + l16) * 40 + quad * 8];
        short8 a1 = *(const short8*)&As[(wr + 16 + l16) * 40 + quad * 8];
        short8 b0 = *(const short8*)&Bs[(wc + l16) * 40 + quad * 8];
        short8 b1 = *(const short8*)&Bs[(wc + 16 + l16) * 40 + quad * 8];
        acc[0][0] = __builtin_amdgcn_mfma_f32_16x16x32_bf16(a0, b0, acc[0][0], 0, 0, 0);
        acc[0][1] = __builtin_amdgcn_mfma_f32_16x16x32_bf16(a0, b1, acc[0][1], 0, 0, 0);
        acc[1][0] = __builtin_amdgcn_mfma_f32_16x16x32_bf16(a1, b0, acc[1][0], 0, 0, 0);
        acc[1][1] = __builtin_amdgcn_mfma_f32_16x16x32_bf16(a1, b1, acc[1][1], 0, 0, 0);
        __syncthreads();
    }

    #pragma unroll
    for (int sr = 0; sr < 2; sr++) {
        #pragma unroll
        for (int sc = 0; sc < 2; sc++) {
            int gc = n0 + wc + sc * 16 + l16;
            if (gc >= N) continue;
            float bvv = 0.f;
            if (HAS_BIAS && addbias)
                bvv = bias[(SPLITK > 1 ? 0 : (long)bz * biasoff) + gc];
            #pragma unroll
            for (int r = 0; r < 4; r++) {
                int gr = m0 + wr + sr * 16 + quad * 4 + r;
                if (gr >= M) continue;
                float v = acc[sr][sc][r] * scale + bvv;
                if (RELU) v = fmaxf(v, 0.f);
                long cidx = cbase + (long)gr * ldc + gc;
                if (OUT_MODE == 0)      ((float*)Cv)[cidx] = v;
                else if (OUT_MODE == 1) ((short*)Cv)[cidx] = f2bfs(v);
                else if (OUT_MODE == 2) ((float*)Cv)[cidx] += v;
                else                    atomicAdd((float*)Cv + cidx, v);
            }
        }
    }
}

// ---------------------------------------------------------------------------
// LN of inputs over INF=256, affine -> bf16. One wave per row.
// ---------------------------------------------------------------------------
__global__ __launch_bounds__(256) void ln_in_k(const float* __restrict__ in,
                                               const float* __restrict__ g,
                                               const float* __restrict__ b,
                                               short* __restrict__ out)
{
    int row  = blockIdx.x * 4 + (threadIdx.x >> 6);
    int lane = threadIdx.x & 63;
    long off = (long)row * 256 + lane * 4;
    f32x4 v4 = *(const f32x4*)(in + off);
    float v[4] = {v4[0], v4[1], v4[2], v4[3]};
    float s = v[0] + v[1] + v[2] + v[3];
    #pragma unroll
    for (int d = 1; d < 64; d <<= 1) s += __shfl_xor(s, d);
    float mean = s * (1.f / 256.f);
    float sq = 0.f;
    #pragma unroll
    for (int k = 0; k < 4; k++) { float dd = v[k] - mean; sq += dd * dd; }
    #pragma unroll
    for (int d = 1; d < 64; d <<= 1) sq += __shfl_xor(sq, d);
    float inv = rsqrtf(sq * (1.f / 256.f) + 1e-5f);
    short* op = out + off;
    #pragma unroll
    for (int k = 0; k < 4; k++)
        op[k] = f2bfs((v[k] - mean) * inv * g[lane * 4 + k] + b[lane * 4 + k]);
}

// ---------------------------------------------------------------------------
// FUSED iteration front-half, one block per batch b (32 blocks, 512 thr):
//   P1 LN(slots) -> s_ln (LDS, swizzled bf16) + slotsbf global [+slots if INIT]
//   P2 kq = s_ln @ M1^T + c1, scaled -> kq_l (LDS bf16)   [MFMA, M1 from L2]
//   P3 dots = x @ kq^T -> dots_l (LDS f32, stride 17)      [MFMA, x from L2]
//   P4 softmax over n (+EPS renorm) -> attn_lb (LDS bf16)  [+attn global last it]
//   P5 up = attn^T @ x  via xbfT                            [MFMA] -> up global
// M=8 shapes use A-row = l16&7 (rows 8-15 are duplicates, discarded on store).
// ---------------------------------------------------------------------------
#define QSCALE 0.022097086912079608f
template<int INIT, int WRITE_ATTN>
__global__ __launch_bounds__(512) void iter_front_k(
    float* __restrict__ slots,
    const float* __restrict__ noise, const float* __restrict__ mu, const float* __restrict__ ls,
    const float* __restrict__ g, const float* __restrict__ b_,
    const short* __restrict__ xbf, const short* __restrict__ xbfT,
    const short* __restrict__ M1bf, const float* __restrict__ c1,
    short* __restrict__ slotsbf, float* __restrict__ up, float* __restrict__ attng)
{
    int b = blockIdx.x, tid = threadIdx.x;
    int w = tid >> 6, lane = tid & 63, quad = lane >> 4, l16 = lane & 15;

    // LDS: dots_l f32[1024][17] @0 (69632) | s_ln bf16 8x256chunks @69632 (32768,
    //      later aliased by attn_lb bf16[8][1024]) | kq_l bf16[16][280] @102400 (8960)
    __shared__ __align__(16) char lds[111360];
    float* dots_l = (float*)lds;
    short* kq_l   = (short*)(lds + 102400);

    // ---- P1: LN of slot row w (full 2048 in one wave, 32 elems/lane)
    {
        int row = b * 8 + w;
        long base = (long)row * 2048 + lane * 32;
        float v[32];
        if (INIT) {
            #pragma unroll
            for (int k = 0; k < 32; k++) {
                int d = lane * 32 + k;
                v[k] = mu[d] + expf(ls[d]) * noise[base + k];
                slots[base + k] = v[k];
            }
        } else {
            #pragma unroll
            for (int k = 0; k < 8; k++)
                *(f32x4*)&v[k * 4] = *(const f32x4*)(slots + base + k * 4);
        }
        float s = 0.f;
        #pragma unroll
        for (int k = 0; k < 32; k++) s += v[k];
        #pragma unroll
        for (int d = 1; d < 64; d <<= 1) s += __shfl_xor(s, d);
        float mean = s * (1.f / 2048.f);
        float sq = 0.f;
        #pragma unroll
        for (int k = 0; k < 32; k++) { float dd = v[k] - mean; sq += dd * dd; }
        #pragma unroll
        for (int d = 1; d < 64; d <<= 1) sq += __shfl_xor(sq, d);
        float inv = rsqrtf(sq * (1.f / 2048.f) + 1e-5f);
        float gv[32], bv[32];
        #pragma unroll
        for (int k = 0; k < 8; k++) {
            *(f32x4*)&gv[k * 4] = *(const f32x4*)(g + lane * 32 + k * 4);
            *(f32x4*)&bv[k * 4] = *(const f32x4*)(b_ + lane * 32 + k * 4);
        }
        #pragma unroll
        for (int j = 0; j < 4; j++) {
            short8 t, tb;
            #pragma unroll
            for (int e = 0; e < 8; e++) {
                int k = j * 8 + e;
                t[e]  = f2bfs((v[k] - mean) * inv * gv[k] + bv[k]);
                tb[e] = f2bfs(v[k]);
            }
            int swz = (lane * 4 + j) ^ w;                       // key = row&7 = w
            *(short8*)(lds + 69632 + w * 4096 + swz * 16) = t;
            *(short8*)(slotsbf + base + j * 8) = tb;
        }
    }
    __syncthreads();

    // ---- P2: kq MFMA. wave w owns i-chunk [w*32, w*32+32)
    {
        f32x4 acc0 = {}, acc1 = {};
        int ar = l16 & 7;
        int i0 = w * 32;
        const short* m1a = M1bf + (long)(i0 + l16) * 2048 + quad * 8;
        const short* m1b = M1bf + (long)(i0 + 16 + l16) * 2048 + quad * 8;
        const char* sb = lds + 69632 + ar * 4096;
        for (int ks = 0; ks < 64; ks++) {
            short8 a  = *(const short8*)(sb + (((ks * 4 + quad) ^ ar) << 4));
            short8 b0 = *(const short8*)(m1a + ks * 32);
            short8 b1 = *(const short8*)(m1b + ks * 32);
            acc0 = __builtin_amdgcn_mfma_f32_16x16x32_bf16(a, b0, acc0, 0, 0, 0);
            acc1 = __builtin_amdgcn_mfma_f32_16x16x32_bf16(a, b1, acc1, 0, 0, 0);
        }
        #pragma unroll
        for (int r = 0; r < 4; r++) {
            int s = quad * 4 + r;
            int i1 = i0 + l16, i2 = i0 + 16 + l16;
            kq_l[s * 280 + i1] = f2bfs((acc0[r] + c1[i1]) * QSCALE);
            kq_l[s * 280 + i2] = f2bfs((acc1[r] + c1[i2]) * QSCALE);
        }
    }
    __syncthreads();

    // ---- P3: dots MFMA. wave w owns n-range [w*128, w*128+128)
    {
        const short* xb = xbf + (long)b * 262144;
        #pragma unroll
        for (int mt = 0; mt < 8; mt++) {
            int m0 = w * 128 + mt * 16;
            f32x4 acc = {};
            const short* ap = xb + (long)(m0 + l16) * 256 + quad * 8;
            #pragma unroll
            for (int ks = 0; ks < 8; ks++) {
                short8 a  = *(const short8*)(ap + ks * 32);
                short8 bb = *(const short8*)(kq_l + l16 * 280 + ks * 32 + quad * 8);
                acc = __builtin_amdgcn_mfma_f32_16x16x32_bf16(a, bb, acc, 0, 0, 0);
            }
            #pragma unroll
            for (int r = 0; r < 4; r++)
                dots_l[(m0 + quad * 4 + r) * 17 + l16] = acc[r];
        }
    }
    __syncthreads();

    // ---- P4: softmax over n for s=w; attn -> LDS bf16 (swizzled) [+global]
    {
        int s = w;
        float v[16];
        float mx = -1e30f;
        #pragma unroll
        for (int k = 0; k < 16; k++) { v[k] = dots_l[(lane + k * 64) * 17 + s]; mx = fmaxf(mx, v[k]); }
        #pragma unroll
        for (int d = 1; d < 64; d <<= 1) mx = fmaxf(mx, __shfl_xor(mx, d));
        float sum = 0.f;
        #pragma unroll
        for (int k = 0; k < 16; k++) { v[k] = expf(v[k] - mx); sum += v[k]; }
        #pragma unroll
        for (int d = 1; d < 64; d <<= 1) sum += __shfl_xor(sum, d);
        float inv = 1.f / sum;
        float sum2 = 0.f;
        #pragma unroll
        for (int k = 0; k < 16; k++) { v[k] = v[k] * inv + 1e-8f; sum2 += v[k]; }
        #pragma unroll
        for (int d = 1; d < 64; d <<= 1) sum2 += __shfl_xor(sum2, d);
        float inv2 = 1.f / sum2;
        #pragma unroll
        for (int k = 0; k < 16; k++) {
            float a = v[k] * inv2;
            int n = lane + k * 64;
            if (WRITE_ATTN) attng[(long)b * 8192 + n * 8 + s] = a;
            *(short*)(lds + 69632 + s * 2048 + (((n >> 3) ^ s) << 4) + (n & 7) * 2) = f2bfs(a);
        }
    }
    __syncthreads();

    // ---- P5: up = attn^T @ x via xbfT. wave w owns i-chunk [w*32, w*32+32)
    {
        int s8 = l16 & 7;
        int i0 = w * 32;
        const short* xtA = xbfT + (long)b * 262144 + (long)(i0 + l16) * 1024 + quad * 8;
        const short* xtB = xtA + 16 * 1024;
        const char* ab = lds + 69632 + s8 * 2048;
        f32x4 acc0 = {}, acc1 = {};
        for (int ks = 0; ks < 32; ks++) {
            short8 a  = *(const short8*)(ab + (((ks * 4 + quad) ^ s8) << 4));
            short8 b0 = *(const short8*)(xtA + ks * 32);
            short8 b1 = *(const short8*)(xtB + ks * 32);
            acc0 = __builtin_amdgcn_mfma_f32_16x16x32_bf16(a, b0, acc0, 0, 0, 0);
            acc1 = __builtin_amdgcn_mfma_f32_16x16x32_bf16(a, b1, acc1, 0, 0, 0);
        }
        #pragma unroll
        for (int r = 0; r < 4; r++) {
            int s = quad * 4 + r;
            if (s < 8) {
                up[(long)b * 2048 + s * 256 + i0 + l16]      = acc0[r];
                up[(long)b * 2048 + s * 256 + i0 + 16 + l16] = acc1[r];
            }
        }
    }
}

// ---------------------------------------------------------------------------
// FUSED per-(nb,b) tail: GRU -> residual block-MLP -> BWA (verified r3 version)
// ---------------------------------------------------------------------------
__global__ __launch_bounds__(512) void resid_bwa_k(
    float* __restrict__ slots,
    const float* __restrict__ gi, const float* __restrict__ gh,
    const float* __restrict__ bih, const float* __restrict__ bhh,
    const float* __restrict__ h4,
    const short* __restrict__ mW1T, const short* __restrict__ mW2T,
    const float* __restrict__ mb1, const float* __restrict__ mb2)
{
    int nb = blockIdx.x, b = blockIdx.y, tid = threadIdx.x;
    int lane = tid & 63, r = tid >> 6;

    __shared__ __align__(16) float ml[64 * 132];
    __shared__ __align__(16) short wlds[8192];
    __shared__ __align__(16) float t1[8 * 128];
    __shared__ __align__(16) float t2[8 * 128];
    __shared__ __align__(16) float sc[8 * 64];

    {
        int p = tid >> 3, t8 = tid & 7;
        const float* src = h4 + (long)(p * 16 + nb) * 128 + t8 * 16;
        f32x4 a0 = *(const f32x4*)src;
        f32x4 a1 = *(const f32x4*)(src + 4);
        f32x4 a2 = *(const f32x4*)(src + 8);
        f32x4 a3 = *(const f32x4*)(src + 12);
        float s = 0.f, sq = 0.f;
        #pragma unroll
        for (int k = 0; k < 4; k++) {
            s  += a0[k] + a1[k] + a2[k] + a3[k];
            sq += a0[k]*a0[k] + a1[k]*a1[k] + a2[k]*a2[k] + a3[k]*a3[k];
        }
        #pragma unroll
        for (int d = 1; d < 8; d <<= 1) { s += __shfl_xor(s, d); sq += __shfl_xor(sq, d); }
        float mean = s * (1.f / 128.f);
        float var = sq * (1.f / 128.f) - mean * mean;
        float inv = rsqrtf(var + 1e-5f);
        float* dst = &ml[p * 132 + t8 * 16];
        #pragma unroll
        for (int k = 0; k < 4; k++) {
            dst[k]      = (a0[k] - mean) * inv;
            dst[4 + k]  = (a1[k] - mean) * inv;
            dst[8 + k]  = (a2[k] - mean) * inv;
            dst[12 + k] = (a3[k] - mean) * inv;
        }
    }

    auto stagew = [&](const short* Wh) {
        #pragma unroll
        for (int pass = 0; pass < 2; pass++) {
            int idx = pass * 4096 + tid * 8;
            short8 v = *(const short8*)(Wh + idx);
            int o = idx >> 7;
            int c = (idx >> 3) & 15;
            int key = (o & 15) ^ ((o >> 4) & 3);
            *(short8*)&wlds[o * 128 + ((c ^ key) << 3)] = v;
        }
    };
    stagew(mW1T + (long)nb * 16384);

    int row = b * 8 + r;
    long grow = (long)row * 6144 + nb * 384;
    long srow = (long)row * 2048 + nb * 128;
    int bb = nb * 384;
    float sv0, sv1;
    {
        float ir0 = gi[grow + lane]       + bih[bb + lane];
        float ir1 = gi[grow + lane + 64]  + bih[bb + lane + 64];
        float iz0 = gi[grow + 128 + lane] + bih[bb + 128 + lane];
        float iz1 = gi[grow + 192 + lane] + bih[bb + 192 + lane];
        float in0 = gi[grow + 256 + lane] + bih[bb + 256 + lane];
        float in1 = gi[grow + 320 + lane] + bih[bb + 320 + lane];
        float hr0 = gh[grow + lane]       + bhh[bb + lane];
        float hr1 = gh[grow + lane + 64]  + bhh[bb + lane + 64];
        float hz0 = gh[grow + 128 + lane] + bhh[bb + 128 + lane];
        float hz1 = gh[grow + 192 + lane] + bhh[bb + 192 + lane];
        float hn0 = gh[grow + 256 + lane] + bhh[bb + 256 + lane];
        float hn1 = gh[grow + 320 + lane] + bhh[bb + 320 + lane];
        float h0 = slots[srow + lane], h1 = slots[srow + lane + 64];
        float rg0 = sigm(ir0 + hr0), rg1 = sigm(ir1 + hr1);
        float zg0 = sigm(iz0 + hz0), zg1 = sigm(iz1 + hz1);
        sv0 = (1.f - zg0) * tanhf(in0 + rg0 * hn0) + zg0 * h0;
        sv1 = (1.f - zg1) * tanhf(in1 + rg1 * hn1) + zg1 * h1;
        float s = sv0 + sv1, sq = sv0 * sv0 + sv1 * sv1;
        #pragma unroll
        for (int d = 1; d < 64; d <<= 1) { s += __shfl_xor(s, d); sq += __shfl_xor(sq, d); }
        float mean = s * (1.f / 128.f);
        float var = sq * (1.f / 128.f) - mean * mean;
        float inv = rsqrtf(var + 1e-5f);
        t1[r * 128 + lane]      = (sv0 - mean) * inv;
        t1[r * 128 + lane + 64] = (sv1 - mean) * inv;
    }
    __syncthreads();

    auto mlpdot = [&](const float* xr) -> float {
        int key = (lane & 15) ^ ((lane >> 4) & 3);
        const short* wrow = &wlds[lane * 128];
        float acc0 = 0.f, acc1 = 0.f;
        #pragma unroll
        for (int c = 0; c < 16; c++) {
            f32x4 x0 = *(const f32x4*)(xr + c * 8);
            f32x4 x1 = *(const f32x4*)(xr + c * 8 + 4);
            short8 w = *(const short8*)(wrow + ((c ^ key) << 3));
            acc0 += x0[0]*bfs2f(w[0]) + x0[1]*bfs2f(w[1]) + x0[2]*bfs2f(w[2]) + x0[3]*bfs2f(w[3]);
            acc1 += x1[0]*bfs2f(w[4]) + x1[1]*bfs2f(w[5]) + x1[2]*bfs2f(w[6]) + x1[3]*bfs2f(w[7]);
        }
        return acc0 + acc1;
    };

    float c0 = mlpdot(&t1[r * 128]);
    __syncthreads();
    stagew(mW1T + (long)nb * 16384 + 8192);
    __syncthreads();
    float c1v = mlpdot(&t1[r * 128]);
    t2[r * 128 + lane]      = fmaxf(c0 + mb1[nb * 128 + lane], 0.f);
    t2[r * 128 + lane + 64] = fmaxf(c1v + mb1[nb * 128 + lane + 64], 0.f);
    __syncthreads();
    stagew(mW2T + (long)nb * 16384);
    __syncthreads();

    float y0 = mlpdot(&t2[r * 128]);
    __syncthreads();
    stagew(mW2T + (long)nb * 16384 + 8192);
    __syncthreads();
    float y1 = mlpdot(&t2[r * 128]);
    {
        y0 += mb2[nb * 128 + lane]      + sv0;
        y1 += mb2[nb * 128 + lane + 64] + sv1;
        float s = y0 + y1, sq = y0 * y0 + y1 * y1;
        #pragma unroll
        for (int d = 1; d < 64; d <<= 1) { s += __shfl_xor(s, d); sq += __shfl_xor(sq, d); }
        float mean = s * (1.f / 128.f);
        float var = sq * (1.f / 128.f) - mean * mean;
        float inv = rsqrtf(var + 1e-5f) * 0.08838834764831845f;
        t1[r * 128 + lane]      = (y0 - mean) * inv;
        t1[r * 128 + lane + 64] = (y1 - mean) * inv;
    }
    __syncthreads();

    {
        const float* qr = &t1[r * 128];
        const float* mr = &ml[lane * 132];
        float acc0 = 0.f, acc1 = 0.f;
        #pragma unroll
        for (int j = 0; j < 128; j += 8) {
            f32x4 q0 = *(const f32x4*)(qr + j);
            f32x4 q1 = *(const f32x4*)(qr + j + 4);
            f32x4 m0 = *(const f32x4*)(mr + j);
            f32x4 m1 = *(const f32x4*)(mr + j + 4);
            acc0 += q0[0]*m0[0] + q0[1]*m0[1] + q0[2]*m0[2] + q0[3]*m0[3];
            acc1 += q1[0]*m1[0] + q1[1]*m1[1] + q1[2]*m1[2] + q1[3]*m1[3];
        }
        float acc = acc0 + acc1;
        float mx = acc;
        #pragma unroll
        for (int d = 1; d < 64; d <<= 1) mx = fmaxf(mx, __shfl_xor(mx, d));
        float e = expf(acc - mx);
        float ss = e;
        #pragma unroll
        for (int d = 1; d < 64; d <<= 1) ss += __shfl_xor(ss, d);
        sc[r * 64 + lane] = e / ss;
    }
    __syncthreads();

    {
        const float* scr = &sc[r * 64];
        float a0 = 0.f, a1 = 0.f;
        #pragma unroll 4
        for (int p = 0; p < 64; p++) {
            float a = scr[p];
            a0 += a * ml[p * 132 + lane];
            a1 += a * ml[p * 132 + 64 + lane];
        }
        float* dst = slots + srow;
        dst[lane] = a0; dst[lane + 64] = a1;
    }
}

// OUTPUT IS FLOAT32
__global__ __launch_bounds__(256) void out_k(const float* __restrict__ slots,
                                             const float* __restrict__ attn,
                                             float* __restrict__ out)
{
    int idx = blockIdx.x * 256 + threadIdx.x;
    out[idx] = (idx < 524288) ? slots[idx] : attn[idx - 524288];
}

// ===========================================================================
extern "C" void kernel_launch(void* const* d_in, const int* in_sizes, int n_in,
                              void* d_out, int out_size, void* d_ws, size_t ws_size,
                              hipStream_t stream)
{
    (void)in_sizes; (void)n_in; (void)out_size; (void)ws_size;
    const float* inputs = (const float*)d_in[0];
    const float* noise  = (const float*)d_in[1];
    const float* smu    = (const float*)d_in[2];
    const float* sls    = (const float*)d_in[3];
    const float* Wq     = (const float*)d_in[4];
    const float* bq     = (const float*)d_in[5];
    const float* Wk     = (const float*)d_in[6];
    /* d_in[7] = bk: softmax(axis=n)-invariant; dropped */
    const float* Wv     = (const float*)d_in[8];
    const float* bv     = (const float*)d_in[9];
    const float* gWih   = (const float*)d_in[10];
    const float* gWhh   = (const float*)d_in[11];
    const float* gbih   = (const float*)d_in[12];
    const float* gbhh   = (const float*)d_in[13];
    const float* mW1    = (const float*)d_in[14];
    const float* mb1    = (const float*)d_in[15];
    const float* mW2    = (const float*)d_in[16];
    const float* mb2    = (const float*)d_in[17];
    const float* cvec   = (const float*)d_in[18];
    const float* cW1    = (const float*)d_in[19];
    const float* cb1    = (const float*)d_in[20];
    const float* cW2    = (const float*)d_in[21];
    const float* cb2    = (const float*)d_in[22];
    const float* cW3    = (const float*)d_in[23];
    const float* cb3    = (const float*)d_in[24];
    const float* cW4    = (const float*)d_in[25];
    const float* cb4    = (const float*)d_in[26];
    const float* nig    = (const float*)d_in[27];
    const float* nib    = (const float*)d_in[28];
    const float* nsg    = (const float*)d_in[29];
    const float* nsb    = (const float*)d_in[30];

    char* w = (char*)d_ws;
    auto take = [&](size_t bytes) -> char* {
        char* p = w;
        w += (bytes + 255) & ~(size_t)255;
        return p;
    };

    float* slots   = (float*)take((size_t)524288 * 4);
    short* xbf     = (short*)take((size_t)32768 * 256 * 2);
    short* xbfT    = (short*)take((size_t)32 * 256 * 1024 * 2);
    short* Wqbf    = (short*)take((size_t)2048 * 2048 * 2);
    short* Wkbf    = (short*)take((size_t)256 * 2048 * 2);
    short* Wvbf    = (short*)take((size_t)256 * 2048 * 2);
    short* gWihbf  = (short*)take((size_t)16 * 384 * 128 * 2);
    short* gWhhbf  = (short*)take((size_t)16 * 384 * 128 * 2);
    short* cvecbf  = (short*)take((size_t)1024 * 128 * 2);
    float* M1f     = (float*)take((size_t)256 * 2048 * 4);
    short* M1bf    = (short*)take((size_t)256 * 2048 * 2);
    short* WvGTbf  = (short*)take((size_t)16 * 384 * 256 * 2);
    float* b1g     = (float*)take((size_t)6144 * 4);
    float* c1      = (float*)take((size_t)256 * 4);
    short* mW1T    = (short*)take((size_t)16 * 128 * 128 * 2);
    short* mW2T    = (short*)take((size_t)16 * 128 * 128 * 2);
    short* cW1T    = (short*)take((size_t)512 * 128 * 2);
    short* cW2T    = (short*)take((size_t)512 * 512 * 2);
    short* cW3T    = (short*)take((size_t)512 * 512 * 2);
    short* cW4T    = (short*)take((size_t)128 * 512 * 2);
    short* hA      = (short*)take((size_t)1024 * 512 * 2);
    short* hB      = (short*)take((size_t)1024 * 512 * 2);
    float* h4      = (float*)take((size_t)1024 * 128 * 4);
    short* slotsbf = (short*)take((size_t)256 * 2048 * 2);
    float* attn    = (float*)take((size_t)32 * 1024 * 8 * 4);
    float* up      = (float*)take((size_t)256 * 256 * 4);
    float* gi      = (float*)take((size_t)256 * 6144 * 4);
    float* gh      = (float*)take((size_t)256 * 6144 * 4);

    // --- prep: converts, transposes, folded weights ------------------------
    cvt_all_k<<<29184, 256, 0, stream>>>(Wq, Wk, Wv, gWih, gWhh, cvec,
                                         Wqbf, Wkbf, Wvbf, gWihbf, gWhhbf, cvecbf, M1f);
    transpose_all_k<<<1152, 256, 0, stream>>>(mW1, mW2, cW1, cW2, cW3, cW4,
                                              mW1T, mW2T, cW1T, cW2T, cW3T, cW4T);
    gemm_bt<3,0,0,0,0,4><<<dim3(4, 32, 4), 256, 0, stream>>>(
        Wkbf, 2048, 0, Wqbf, 2048, 0, M1f, 2048, 0, nullptr, 0, 256, 2048, 2048, 1.f);
    cvt_m1_k<<<512, 256, 0, stream>>>(M1f, M1bf);
    gemm_bt<1,0,0,0,0,1><<<dim3(6, 4, 16), 256, 0, stream>>>(
        gWihbf, 128, 49152, Wvbf, 2048, 128, WvGTbf, 256, 98304, nullptr, 0, 384, 256, 128, 1.f);
    b1c1_k<<<280, 256, 0, stream>>>(bq, Wk, bv, gWih, c1, b1g);

    ln_in_k<<<8192, 256, 0, stream>>>(inputs, nig, nib, xbf);
    xt_k<<<dim3(8, 32, 32), 256, 0, stream>>>(xbf, xbfT);

    // --- concept memory (iteration-invariant) ------------------------------
    gemm_bt<1,1,1,0,0,1><<<dim3(16, 8, 1), 256, 0, stream>>>(cvecbf, 128, 0, cW1T, 128, 0, hA, 512, 0, cb1, 0, 1024, 512, 128, 1.f);
    gemm_bt<1,1,1,0,0,1><<<dim3(16, 8, 1), 256, 0, stream>>>(hA, 512, 0, cW2T, 512, 0, hB, 512, 0, cb2, 0, 1024, 512, 512, 1.f);
    gemm_bt<1,1,1,0,0,1><<<dim3(16, 8, 1), 256, 0, stream>>>(hB, 512, 0, cW3T, 512, 0, hA, 512, 0, cb3, 0, 1024, 512, 512, 1.f);
    gemm_bt<0,0,1,0,0,1><<<dim3(16, 2, 1), 256, 0, stream>>>(hA, 512, 0, cW4T, 512, 0, h4, 128, 0, cb4, 0, 1024, 128, 512, 1.f);

    for (int it = 0; it < 3; ++it) {
        if (it == 0)
            iter_front_k<1,0><<<32, 512, 0, stream>>>(slots, noise, smu, sls, nsg, nsb,
                                                      xbf, xbfT, M1bf, c1, slotsbf, up, attn);
        else if (it == 1)
            iter_front_k<0,0><<<32, 512, 0, stream>>>(slots, noise, smu, sls, nsg, nsb,
                                                      xbf, xbfT, M1bf, c1, slotsbf, up, attn);
        else
            iter_front_k<0,1><<<32, 512, 0, stream>>>(slots, noise, smu, sls, nsg, nsb,
                                                      xbf, xbfT, M1bf, c1, slotsbf, up, attn);
        // gi = u' @ WvGT + b1g   (Wv folded into gWih; bv folded into b1g)
        gemm_bt<0,0,1,1,0,1><<<dim3(4, 6, 16), 256, 0, stream>>>(
            up, 256, 0, WvGTbf, 256, 98304, gi, 6144, 384, b1g, 384, 256, 384, 256, 1.f);
        gemm_bt<0,0,0,0,0,1><<<dim3(4, 6, 16), 256, 0, stream>>>(
            slotsbf, 2048, 128, gWhhbf, 128, 49152, gh, 6144, 384, nullptr, 0, 256, 384, 128, 1.f);
        // fused: GRU + residual block-MLP + block-wise attention over prototypes
        resid_bwa_k<<<dim3(16, 32), 512, 0, stream>>>(slots, gi, gh, gbih, gbhh,
                                                      h4, mW1T, mW2T, mb1, mb2);
    }
    out_k<<<3072, 256, 0, stream>>>(slots, attn, (float*)d_out);
}

// Round 6
// 522.538 us; speedup vs baseline: 1.0584x; 1.0584x over previous
//
#include <hip/hip_runtime.h>

typedef __attribute__((ext_vector_type(8))) short short8;
typedef __attribute__((ext_vector_type(4))) float f32x4;

#define DEV static __device__ __forceinline__

DEV float bfs2f(short s) {
    union { unsigned int u; float f; } c;
    c.u = ((unsigned int)(unsigned short)s) << 16;
    return c.f;
}
DEV short f2bfs(float f) {
    union { float f; unsigned int u; } c;
    c.f = f;
    unsigned int u = c.u;
    return (short)((u + 0x7fffu + ((u >> 16) & 1u)) >> 16);  // RNE
}
DEV int imin(int a, int b) { return a < b ? a : b; }
DEV float sigm(float x) { return 1.f / (1.f + expf(-x)); }

// ---------------------------------------------------------------------------
// Fused f32->bf16 convert of all plain weights + zero of M1f (one launch).
// ---------------------------------------------------------------------------
__global__ __launch_bounds__(256) void cvt_all_k(
    const float* __restrict__ Wq, const float* __restrict__ Wk, const float* __restrict__ Wv,
    const float* __restrict__ gih, const float* __restrict__ ghh, const float* __restrict__ cv,
    short* __restrict__ dWq, short* __restrict__ dWk, short* __restrict__ dWv,
    short* __restrict__ dgih, short* __restrict__ dghh, short* __restrict__ dcv,
    float* __restrict__ M1f)
{
    long i = (long)blockIdx.x * 256 + threadIdx.x;
    const float* s; short* d; long o;
    if      (i < 4194304) { s = Wq;  d = dWq;  o = i; }
    else if (i < 4718592) { s = Wk;  d = dWk;  o = i - 4194304; }
    else if (i < 5242880) { s = Wv;  d = dWv;  o = i - 4718592; }
    else if (i < 6029312) { s = gih; d = dgih; o = i - 5242880; }
    else if (i < 6815744) { s = ghh; d = dghh; o = i - 6029312; }
    else if (i < 6946816) { s = cv;  d = dcv;  o = i - 6815744; }
    else if (i < 7471104) { M1f[i - 6946816] = 0.f; return; }
    else return;
    d[o] = f2bfs(s[o]);
}

// ---------------------------------------------------------------------------
// All weight transposes (f32 [R,C] -> bf16 [C,R]) in ONE launch.
// ---------------------------------------------------------------------------
__global__ __launch_bounds__(256) void transpose_all_k(
    const float* __restrict__ mW1, const float* __restrict__ mW2,
    const float* __restrict__ cW1, const float* __restrict__ cW2,
    const float* __restrict__ cW3, const float* __restrict__ cW4,
    short* __restrict__ mW1T, short* __restrict__ mW2T,
    short* __restrict__ cW1T, short* __restrict__ cW2T,
    short* __restrict__ cW3T, short* __restrict__ cW4T)
{
    int id = blockIdx.x;
    const float* in; short* out; int R, C, tx, ty;
    if (id < 256)       { int z = id >> 4, t = id & 15; in = mW1 + z * 16384; out = mW1T + z * 16384; R = 128; C = 128; tx = t & 3;  ty = t >> 2; }
    else if (id < 512)  { id -= 256; int z = id >> 4, t = id & 15; in = mW2 + z * 16384; out = mW2T + z * 16384; R = 128; C = 128; tx = t & 3;  ty = t >> 2; }
    else if (id < 576)  { id -= 512;  in = cW1; out = cW1T; R = 128; C = 512; tx = id & 15; ty = id >> 4; }
    else if (id < 832)  { id -= 576;  in = cW2; out = cW2T; R = 512; C = 512; tx = id & 15; ty = id >> 4; }
    else if (id < 1088) { id -= 832;  in = cW3; out = cW3T; R = 512; C = 512; tx = id & 15; ty = id >> 4; }
    else                { id -= 1088; in = cW4; out = cW4T; R = 512; C = 128; tx = id & 3;  ty = id >> 2; }
    __shared__ short t[32][33];
    int c0 = tx * 32, r0 = ty * 32;
    int x = threadIdx.x & 31, y = threadIdx.x >> 5;
    #pragma unroll
    for (int k = 0; k < 32; k += 8) t[y + k][x] = f2bfs(in[(long)(r0 + y + k) * C + (c0 + x)]);
    __syncthreads();
    #pragma unroll
    for (int k = 0; k < 32; k += 8) out[(long)(c0 + y + k) * R + (r0 + x)] = t[x][y + k];
}

// ---------------------------------------------------------------------------
// Merged folded-bias prep: c1 and b1g
// ---------------------------------------------------------------------------
__global__ __launch_bounds__(256) void b1c1_k(const float* __restrict__ bq,
                                              const float* __restrict__ Wk,
                                              const float* __restrict__ bv,
                                              const float* __restrict__ gWih,
                                              float* __restrict__ c1,
                                              float* __restrict__ b1g)
{
    int bid = blockIdx.x, tid = threadIdx.x;
    __shared__ float red[4];
    if (bid < 256) {
        const float* row = Wk + (long)bid * 2048;
        float acc = 0.f;
        for (int d = tid; d < 2048; d += 256) acc += bq[d] * row[d];
        #pragma unroll
        for (int d = 1; d < 64; d <<= 1) acc += __shfl_xor(acc, d);
        int w = tid >> 6;
        if ((tid & 63) == 0) red[w] = acc;
        __syncthreads();
        if (tid == 0) c1[bid] = red[0] + red[1] + red[2] + red[3];
    } else {
        int t = (bid - 256) * 256 + tid;   // < 6144
        int nb = t / 384, g = t % 384;
        const float* wrow = gWih + (long)nb * 49152 + (long)g * 128;
        const float* bp = bv + nb * 128;
        float acc = 0.f;
        for (int j = 0; j < 128; j++) acc += bp[j] * wrow[j];
        b1g[t] = acc;
    }
}

// M1f (f32, 524288) -> M1bf (bf16)
__global__ __launch_bounds__(256) void cvt_m1_k(const float* __restrict__ in,
                                                short* __restrict__ out)
{
    int i = (blockIdx.x * 256 + threadIdx.x) * 4;
    f32x4 v = *(const f32x4*)(in + i);
    out[i]     = f2bfs(v[0]);
    out[i + 1] = f2bfs(v[1]);
    out[i + 2] = f2bfs(v[2]);
    out[i + 3] = f2bfs(v[3]);
}

// ---------------------------------------------------------------------------
// Tiled MFMA GEMM core (body of the verified r3 gemm_bt, as a device fn).
// ---------------------------------------------------------------------------
template<int OUT_MODE, int RELU, int HAS_BIAS, int A_F32, int B_F32>
DEV void gemm_core(const void* __restrict__ Av, long lda, long abase,
                   const void* __restrict__ Btv, long ldb, long bbase,
                   void* __restrict__ Cv, long ldc, long cbase,
                   const float* __restrict__ bias, long biasbase, int addbias,
                   int M, int N, int K, float scale, int kbeg, int kend,
                   short* As, short* Bs)
{
    const int tid  = threadIdx.x;
    const int wave = tid >> 6, lane = tid & 63;
    const int quad = lane >> 4, l16 = lane & 15;
    const int wr = (wave >> 1) * 32, wc = (wave & 1) * 32;
    const int m0 = blockIdx.x * 64, n0 = blockIdx.y * 64;

    f32x4 acc[2][2] = {};

    const int lrow = tid >> 2;
    const int lk   = (tid & 3) * 8;
    const int arow = imin(m0 + lrow, M - 1);
    const int brow = imin(n0 + lrow, N - 1);
    short* asd = &As[lrow * 40 + lk];
    short* bsd = &Bs[lrow * 40 + lk];

    short8 arS = {}, brS = {};
    f32x4 arF0 = {}, arF1 = {}, brF0 = {}, brF1 = {};

    auto loadA = [&](int k0) {
        if (A_F32) {
            const float* p = (const float*)Av + abase + (long)arow * lda + lk + k0;
            arF0 = *(const f32x4*)p; arF1 = *(const f32x4*)(p + 4);
        } else {
            arS = *(const short8*)((const short*)Av + abase + (long)arow * lda + lk + k0);
        }
    };
    auto loadB = [&](int k0) {
        if (B_F32) {
            const float* p = (const float*)Btv + bbase + (long)brow * ldb + lk + k0;
            brF0 = *(const f32x4*)p; brF1 = *(const f32x4*)(p + 4);
        } else {
            brS = *(const short8*)((const short*)Btv + bbase + (long)brow * ldb + lk + k0);
        }
    };
    auto stage = [&]() {
        if (A_F32) {
            short8 t;
            #pragma unroll
            for (int j = 0; j < 4; j++) { t[j] = f2bfs(arF0[j]); t[j + 4] = f2bfs(arF1[j]); }
            *(short8*)asd = t;
        } else *(short8*)asd = arS;
        if (B_F32) {
            short8 t;
            #pragma unroll
            for (int j = 0; j < 4; j++) { t[j] = f2bfs(brF0[j]); t[j + 4] = f2bfs(brF1[j]); }
            *(short8*)bsd = t;
        } else *(short8*)bsd = brS;
    };

    loadA(kbeg); loadB(kbeg);
    for (int k0 = kbeg; k0 < kend; k0 += 32) {
        stage();
        __syncthreads();
        if (k0 + 32 < kend) { loadA(k0 + 32); loadB(k0 + 32); }
        short8 a0 = *(const short8*)&As[(wr + l16) * 40 + quad * 8];
        short8 a1 = *(const short8*)&As[(wr + 16 + l16) * 40 + quad * 8];
        short8 b0 = *(const short8*)&Bs[(wc + l16) * 40 + quad * 8];
        short8 b1 = *(const short8*)&Bs[(wc + 16 + l16) * 40 + quad * 8];
        acc[0][0] = __builtin_amdgcn_mfma_f32_16x16x32_bf16(a0, b0, acc[0][0], 0, 0, 0);
        acc[0][1] = __builtin_amdgcn_mfma_f32_16x16x32_bf16(a0, b1, acc[0][1], 0, 0, 0);
        acc[1][0] = __builtin_amdgcn_mfma_f32_16x16x32_bf16(a1, b0, acc[1][0], 0, 0, 0);
        acc[1][1] = __builtin_amdgcn_mfma_f32_16x16x32_bf16(a1, b1, acc[1][1], 0, 0, 0);
        __syncthreads();
    }

    #pragma unroll
    for (int sr = 0; sr < 2; sr++) {
        #pragma unroll
        for (int sc = 0; sc < 2; sc++) {
            int gc = n0 + wc + sc * 16 + l16;
            if (gc >= N) continue;
            float bvv = 0.f;
            if (HAS_BIAS && addbias) bvv = bias[biasbase + gc];
            #pragma unroll
            for (int r = 0; r < 4; r++) {
                int gr = m0 + wr + sr * 16 + quad * 4 + r;
                if (gr >= M) continue;
                float v = acc[sr][sc][r] * scale + bvv;
                if (RELU) v = fmaxf(v, 0.f);
                long cidx = cbase + (long)gr * ldc + gc;
                if (OUT_MODE == 0)      ((float*)Cv)[cidx] = v;
                else if (OUT_MODE == 1) ((short*)Cv)[cidx] = f2bfs(v);
                else if (OUT_MODE == 2) ((float*)Cv)[cidx] += v;
                else                    atomicAdd((float*)Cv + cidx, v);
            }
        }
    }
}

template<int OUT_MODE, int RELU, int HAS_BIAS, int A_F32, int B_F32, int SPLITK>
__global__ __launch_bounds__(256) void gemm_bt(
    const void* __restrict__ Av, long lda, long aoff,
    const void* __restrict__ Btv, long ldb, long boff,
    void* __restrict__ Cv, long ldc, long coff,
    const float* __restrict__ bias, long biasoff,
    int M, int N, int K, float scale)
{
    __shared__ __align__(16) short As[64 * 40];
    __shared__ __align__(16) short Bs[64 * 40];
    const int bz = blockIdx.z;
    long abase, bbase, cbase, biasbase;
    int kbeg, kend, addbias;
    if (SPLITK > 1) {
        int ks = K / SPLITK;
        kbeg = bz * ks; kend = kbeg + ks;
        abase = 0; bbase = 0; cbase = 0; biasbase = 0; addbias = (bz == 0);
    } else {
        kbeg = 0; kend = K;
        abase = (long)bz * aoff; bbase = (long)bz * boff; cbase = (long)bz * coff;
        biasbase = (long)bz * biasoff; addbias = 1;
    }
    gemm_core<OUT_MODE, RELU, HAS_BIAS, A_F32, B_F32>(
        Av, lda, abase, Btv, ldb, bbase, Cv, ldc, cbase,
        bias, biasbase, addbias, M, N, K, scale, kbeg, kend, As, Bs);
}

// gi = up @ WvGT + b1g  (z<16)  and  gh = slotsbf @ gWhh  (z>=16), one launch.
__global__ __launch_bounds__(256) void gemm_gigh(
    const float* __restrict__ up, const short* __restrict__ WvGT,
    const float* __restrict__ b1g,
    const short* __restrict__ slotsbf, const short* __restrict__ gWhh,
    float* __restrict__ gi, float* __restrict__ gh)
{
    __shared__ __align__(16) short As[64 * 40];
    __shared__ __align__(16) short Bs[64 * 40];
    int z = blockIdx.z;
    if (z < 16) {
        long nb = z;
        gemm_core<0, 0, 1, 1, 0>(up, 256, 0, WvGT, 256, nb * 98304,
                                 gi, 6144, nb * 384, b1g, nb * 384, 1,
                                 256, 384, 256, 1.f, 0, 256, As, Bs);
    } else {
        long nb = z - 16;
        gemm_core<0, 0, 0, 0, 0>(slotsbf, 2048, nb * 128, gWhh, 128, nb * 49152,
                                 gh, 6144, nb * 384, nullptr, 0, 1,
                                 256, 384, 128, 1.f, 0, 128, As, Bs);
    }
}

// ---------------------------------------------------------------------------
// LN of inputs over INF=256, affine -> bf16. One wave per row.
// ---------------------------------------------------------------------------
__global__ __launch_bounds__(256) void ln_in_k(const float* __restrict__ in,
                                               const float* __restrict__ g,
                                               const float* __restrict__ b,
                                               short* __restrict__ out)
{
    int row  = blockIdx.x * 4 + (threadIdx.x >> 6);
    int lane = threadIdx.x & 63;
    long off = (long)row * 256 + lane * 4;
    f32x4 v4 = *(const f32x4*)(in + off);
    float v[4] = {v4[0], v4[1], v4[2], v4[3]};
    float s = v[0] + v[1] + v[2] + v[3];
    #pragma unroll
    for (int d = 1; d < 64; d <<= 1) s += __shfl_xor(s, d);
    float mean = s * (1.f / 256.f);
    float sq = 0.f;
    #pragma unroll
    for (int k = 0; k < 4; k++) { float dd = v[k] - mean; sq += dd * dd; }
    #pragma unroll
    for (int d = 1; d < 64; d <<= 1) sq += __shfl_xor(sq, d);
    float inv = rsqrtf(sq * (1.f / 256.f) + 1e-5f);
    short* op = out + off;
    #pragma unroll
    for (int k = 0; k < 4; k++)
        op[k] = f2bfs((v[k] - mean) * inv * g[lane * 4 + k] + b[lane * 4 + k]);
}

// ---------------------------------------------------------------------------
// LN of slots over 2048 -> s_ln bf16; raw slots -> bf16; zero kqf. Block/row.
// INIT=1: first materialize slots = mu + exp(ls)*noise.
// ---------------------------------------------------------------------------
template<int INIT>
__global__ __launch_bounds__(256) void ln_slots_k(float* __restrict__ slots,
                                                  const float* __restrict__ noise,
                                                  const float* __restrict__ mu,
                                                  const float* __restrict__ ls,
                                                  const float* __restrict__ g,
                                                  const float* __restrict__ b,
                                                  short* __restrict__ s_ln,
                                                  short* __restrict__ slotsbf,
                                                  float* __restrict__ kqf)
{
    int row = blockIdx.x, tid = threadIdx.x;
    kqf[row * 256 + tid] = 0.f;  // pre-zero for split-K atomic kq GEMM
    long base = (long)row * 2048 + tid * 8;
    float v[8];
    if (INIT) {
        #pragma unroll
        for (int k = 0; k < 8; k++) {
            int d = tid * 8 + k;
            v[k] = mu[d] + expf(ls[d]) * noise[base + k];
            slots[base + k] = v[k];
        }
    } else {
        *(f32x4*)&v[0] = *(const f32x4*)(slots + base);
        *(f32x4*)&v[4] = *(const f32x4*)(slots + base + 4);
    }
    float s = 0.f;
    #pragma unroll
    for (int k = 0; k < 8; k++) s += v[k];
    #pragma unroll
    for (int d = 1; d < 64; d <<= 1) s += __shfl_xor(s, d);
    __shared__ float wsum[4], wsq[4];
    int w = tid >> 6, lane = tid & 63;
    if (lane == 0) wsum[w] = s;
    __syncthreads();
    float mean = (wsum[0] + wsum[1] + wsum[2] + wsum[3]) * (1.f / 2048.f);
    float sq = 0.f;
    #pragma unroll
    for (int k = 0; k < 8; k++) { float dd = v[k] - mean; sq += dd * dd; }
    #pragma unroll
    for (int d = 1; d < 64; d <<= 1) sq += __shfl_xor(sq, d);
    if (lane == 0) wsq[w] = sq;
    __syncthreads();
    float var = (wsq[0] + wsq[1] + wsq[2] + wsq[3]) * (1.f / 2048.f);
    float inv = rsqrtf(var + 1e-5f);
    #pragma unroll
    for (int k = 0; k < 8; k++) {
        float xn = (v[k] - mean) * inv;
        s_ln[base + k]     = f2bfs(xn * g[tid * 8 + k] + b[tid * 8 + k]);
        slotsbf[base + k] = f2bfs(v[k]);
    }
}

// ---------------------------------------------------------------------------
// FUSED softmax(+EPS renorm) + u' per (s,b) block, 256 threads.
//   a[n] = renorm(softmax_n(dots[b,n,s]));  up[b,s,i] = sum_n a[n]*x[b,n,i]
// x reads are coalesced over i=tid; a[] broadcast from LDS. No atomics.
// WRITE_ATTN: also write a to attng (d_out attn region) — last iteration only.
// ---------------------------------------------------------------------------
template<int WRITE_ATTN>
__global__ __launch_bounds__(256) void smup_k(const float* __restrict__ dots,
                                              const short* __restrict__ xbf,
                                              float* __restrict__ up,
                                              float* __restrict__ attng)
{
    int s = blockIdx.x, b = blockIdx.y, tid = threadIdx.x;
    int w = tid >> 6, lane = tid & 63;
    __shared__ float a_l[1024];
    __shared__ float red[8];

    const float* dp = dots + (long)b * 8192 + s;
    float v[4];
    float mx = -1e30f;
    #pragma unroll
    for (int j = 0; j < 4; j++) { v[j] = dp[(tid + j * 256) * 8]; mx = fmaxf(mx, v[j]); }
    #pragma unroll
    for (int d = 1; d < 64; d <<= 1) mx = fmaxf(mx, __shfl_xor(mx, d));
    if (lane == 0) red[w] = mx;
    __syncthreads();
    mx = fmaxf(fmaxf(red[0], red[1]), fmaxf(red[2], red[3]));
    float sum = 0.f;
    #pragma unroll
    for (int j = 0; j < 4; j++) { v[j] = expf(v[j] - mx); sum += v[j]; }
    #pragma unroll
    for (int d = 1; d < 64; d <<= 1) sum += __shfl_xor(sum, d);
    if (lane == 0) red[4 + w] = sum;
    __syncthreads();
    sum = red[4] + red[5] + red[6] + red[7];
    float inv = 1.f / sum;
    float sum2 = 0.f;
    #pragma unroll
    for (int j = 0; j < 4; j++) { v[j] = v[j] * inv + 1e-8f; sum2 += v[j]; }
    #pragma unroll
    for (int d = 1; d < 64; d <<= 1) sum2 += __shfl_xor(sum2, d);
    if (lane == 0) red[w] = sum2;   // red[0..3] reads above happened pre-barrier
    __syncthreads();
    float inv2 = 1.f / (red[0] + red[1] + red[2] + red[3]);
    #pragma unroll
    for (int j = 0; j < 4; j++) {
        float a = v[j] * inv2;
        int n = tid + j * 256;
        a_l[n] = a;
        if (WRITE_ATTN) attng[(long)b * 8192 + n * 8 + s] = a;
    }
    __syncthreads();

    // up: i = tid, coalesced x reads, a broadcast from LDS
    const short* xp = xbf + (long)b * 262144 + tid;
    float acc = 0.f;
    #pragma unroll 8
    for (int n = 0; n < 1024; n++) acc += a_l[n] * bfs2f(xp[n * 256]);
    up[(long)b * 2048 + s * 256 + tid] = acc;
}

// ---------------------------------------------------------------------------
// FUSED per-(nb,b) tail: GRU -> residual block-MLP -> BWA (verified r3 version)
// WRITE_OUT: also write final slots into d_out slots region (last iteration).
// ---------------------------------------------------------------------------
template<int WRITE_OUT>
__global__ __launch_bounds__(512) void resid_bwa_k(
    float* __restrict__ slots,
    const float* __restrict__ gi, const float* __restrict__ gh,
    const float* __restrict__ bih, const float* __restrict__ bhh,
    const float* __restrict__ h4,
    const short* __restrict__ mW1T, const short* __restrict__ mW2T,
    const float* __restrict__ mb1, const float* __restrict__ mb2,
    float* __restrict__ outp)
{
    int nb = blockIdx.x, b = blockIdx.y, tid = threadIdx.x;
    int lane = tid & 63, r = tid >> 6;

    __shared__ __align__(16) float ml[64 * 132];
    __shared__ __align__(16) short wlds[8192];
    __shared__ __align__(16) float t1[8 * 128];
    __shared__ __align__(16) float t2[8 * 128];
    __shared__ __align__(16) float sc[8 * 64];

    {
        int p = tid >> 3, t8 = tid & 7;
        const float* src = h4 + (long)(p * 16 + nb) * 128 + t8 * 16;
        f32x4 a0 = *(const f32x4*)src;
        f32x4 a1 = *(const f32x4*)(src + 4);
        f32x4 a2 = *(const f32x4*)(src + 8);
        f32x4 a3 = *(const f32x4*)(src + 12);
        float s = 0.f, sq = 0.f;
        #pragma unroll
        for (int k = 0; k < 4; k++) {
            s  += a0[k] + a1[k] + a2[k] + a3[k];
            sq += a0[k]*a0[k] + a1[k]*a1[k] + a2[k]*a2[k] + a3[k]*a3[k];
        }
        #pragma unroll
        for (int d = 1; d < 8; d <<= 1) { s += __shfl_xor(s, d); sq += __shfl_xor(sq, d); }
        float mean = s * (1.f / 128.f);
        float var = sq * (1.f / 128.f) - mean * mean;
        float inv = rsqrtf(var + 1e-5f);
        float* dst = &ml[p * 132 + t8 * 16];
        #pragma unroll
        for (int k = 0; k < 4; k++) {
            dst[k]      = (a0[k] - mean) * inv;
            dst[4 + k]  = (a1[k] - mean) * inv;
            dst[8 + k]  = (a2[k] - mean) * inv;
            dst[12 + k] = (a3[k] - mean) * inv;
        }
    }

    auto stagew = [&](const short* Wh) {
        #pragma unroll
        for (int pass = 0; pass < 2; pass++) {
            int idx = pass * 4096 + tid * 8;
            short8 v = *(const short8*)(Wh + idx);
            int o = idx >> 7;
            int c = (idx >> 3) & 15;
            int key = (o & 15) ^ ((o >> 4) & 3);
            *(short8*)&wlds[o * 128 + ((c ^ key) << 3)] = v;
        }
    };
    stagew(mW1T + (long)nb * 16384);

    int row = b * 8 + r;
    long grow = (long)row * 6144 + nb * 384;
    long srow = (long)row * 2048 + nb * 128;
    int bb = nb * 384;
    float sv0, sv1;
    {
        float ir0 = gi[grow + lane]       + bih[bb + lane];
        float ir1 = gi[grow + lane + 64]  + bih[bb + lane + 64];
        float iz0 = gi[grow + 128 + lane] + bih[bb + 128 + lane];
        float iz1 = gi[grow + 192 + lane] + bih[bb + 192 + lane];
        float in0 = gi[grow + 256 + lane] + bih[bb + 256 + lane];
        float in1 = gi[grow + 320 + lane] + bih[bb + 320 + lane];
        float hr0 = gh[grow + lane]       + bhh[bb + lane];
        float hr1 = gh[grow + lane + 64]  + bhh[bb + lane + 64];
        float hz0 = gh[grow + 128 + lane] + bhh[bb + 128 + lane];
        float hz1 = gh[grow + 192 + lane] + bhh[bb + 192 + lane];
        float hn0 = gh[grow + 256 + lane] + bhh[bb + 256 + lane];
        float hn1 = gh[grow + 320 + lane] + bhh[bb + 320 + lane];
        float h0 = slots[srow + lane], h1 = slots[srow + lane + 64];
        float rg0 = sigm(ir0 + hr0), rg1 = sigm(ir1 + hr1);
        float zg0 = sigm(iz0 + hz0), zg1 = sigm(iz1 + hz1);
        sv0 = (1.f - zg0) * tanhf(in0 + rg0 * hn0) + zg0 * h0;
        sv1 = (1.f - zg1) * tanhf(in1 + rg1 * hn1) + zg1 * h1;
        float s = sv0 + sv1, sq = sv0 * sv0 + sv1 * sv1;
        #pragma unroll
        for (int d = 1; d < 64; d <<= 1) { s += __shfl_xor(s, d); sq += __shfl_xor(sq, d); }
        float mean = s * (1.f / 128.f);
        float var = sq * (1.f / 128.f) - mean * mean;
        float inv = rsqrtf(var + 1e-5f);
        t1[r * 128 + lane]      = (sv0 - mean) * inv;
        t1[r * 128 + lane + 64] = (sv1 - mean) * inv;
    }
    __syncthreads();

    auto mlpdot = [&](const float* xr) -> float {
        int key = (lane & 15) ^ ((lane >> 4) & 3);
        const short* wrow = &wlds[lane * 128];
        float acc0 = 0.f, acc1 = 0.f;
        #pragma unroll
        for (int c = 0; c < 16; c++) {
            f32x4 x0 = *(const f32x4*)(xr + c * 8);
            f32x4 x1 = *(const f32x4*)(xr + c * 8 + 4);
            short8 w = *(const short8*)(wrow + ((c ^ key) << 3));
            acc0 += x0[0]*bfs2f(w[0]) + x0[1]*bfs2f(w[1]) + x0[2]*bfs2f(w[2]) + x0[3]*bfs2f(w[3]);
            acc1 += x1[0]*bfs2f(w[4]) + x1[1]*bfs2f(w[5]) + x1[2]*bfs2f(w[6]) + x1[3]*bfs2f(w[7]);
        }
        return acc0 + acc1;
    };

    float c0 = mlpdot(&t1[r * 128]);
    __syncthreads();
    stagew(mW1T + (long)nb * 16384 + 8192);
    __syncthreads();
    float c1v = mlpdot(&t1[r * 128]);
    t2[r * 128 + lane]      = fmaxf(c0 + mb1[nb * 128 + lane], 0.f);
    t2[r * 128 + lane + 64] = fmaxf(c1v + mb1[nb * 128 + lane + 64], 0.f);
    __syncthreads();
    stagew(mW2T + (long)nb * 16384);
    __syncthreads();

    float y0 = mlpdot(&t2[r * 128]);
    __syncthreads();
    stagew(mW2T + (long)nb * 16384 + 8192);
    __syncthreads();
    float y1 = mlpdot(&t2[r * 128]);
    {
        y0 += mb2[nb * 128 + lane]      + sv0;
        y1 += mb2[nb * 128 + lane + 64] + sv1;
        float s = y0 + y1, sq = y0 * y0 + y1 * y1;
        #pragma unroll
        for (int d = 1; d < 64; d <<= 1) { s += __shfl_xor(s, d); sq += __shfl_xor(sq, d); }
        float mean = s * (1.f / 128.f);
        float var = sq * (1.f / 128.f) - mean * mean;
        float inv = rsqrtf(var + 1e-5f) * 0.08838834764831845f;
        t1[r * 128 + lane]      = (y0 - mean) * inv;
        t1[r * 128 + lane + 64] = (y1 - mean) * inv;
    }
    __syncthreads();

    {
        const float* qr = &t1[r * 128];
        const float* mr = &ml[lane * 132];
        float acc0 = 0.f, acc1 = 0.f;
        #pragma unroll
        for (int j = 0; j < 128; j += 8) {
            f32x4 q0 = *(const f32x4*)(qr + j);
            f32x4 q1 = *(const f32x4*)(qr + j + 4);
            f32x4 m0 = *(const f32x4*)(mr + j);
            f32x4 m1 = *(const f32x4*)(mr + j + 4);
            acc0 += q0[0]*m0[0] + q0[1]*m0[1] + q0[2]*m0[2] + q0[3]*m0[3];
            acc1 += q1[0]*m1[0] + q1[1]*m1[1] + q1[2]*m1[2] + q1[3]*m1[3];
        }
        float acc = acc0 + acc1;
        float mx = acc;
        #pragma unroll
        for (int d = 1; d < 64; d <<= 1) mx = fmaxf(mx, __shfl_xor(mx, d));
        float e = expf(acc - mx);
        float ss = e;
        #pragma unroll
        for (int d = 1; d < 64; d <<= 1) ss += __shfl_xor(ss, d);
        sc[r * 64 + lane] = e / ss;
    }
    __syncthreads();

    {
        const float* scr = &sc[r * 64];
        float a0 = 0.f, a1 = 0.f;
        #pragma unroll 4
        for (int p = 0; p < 64; p++) {
            float a = scr[p];
            a0 += a * ml[p * 132 + lane];
            a1 += a * ml[p * 132 + 64 + lane];
        }
        float* dst = slots + srow;
        dst[lane] = a0; dst[lane + 64] = a1;
        if (WRITE_OUT) {
            outp[srow + lane] = a0; outp[srow + lane + 64] = a1;
        }
    }
}

// ===========================================================================
extern "C" void kernel_launch(void* const* d_in, const int* in_sizes, int n_in,
                              void* d_out, int out_size, void* d_ws, size_t ws_size,
                              hipStream_t stream)
{
    (void)in_sizes; (void)n_in; (void)out_size; (void)ws_size;
    const float* inputs = (const float*)d_in[0];
    const float* noise  = (const float*)d_in[1];
    const float* smu    = (const float*)d_in[2];
    const float* sls    = (const float*)d_in[3];
    const float* Wq     = (const float*)d_in[4];
    const float* bq     = (const float*)d_in[5];
    const float* Wk     = (const float*)d_in[6];
    /* d_in[7] = bk: softmax(axis=n)-invariant; dropped */
    const float* Wv     = (const float*)d_in[8];
    const float* bv     = (const float*)d_in[9];
    const float* gWih   = (const float*)d_in[10];
    const float* gWhh   = (const float*)d_in[11];
    const float* gbih   = (const float*)d_in[12];
    const float* gbhh   = (const float*)d_in[13];
    const float* mW1    = (const float*)d_in[14];
    const float* mb1    = (const float*)d_in[15];
    const float* mW2    = (const float*)d_in[16];
    const float* mb2    = (const float*)d_in[17];
    const float* cvec   = (const float*)d_in[18];
    const float* cW1    = (const float*)d_in[19];
    const float* cb1    = (const float*)d_in[20];
    const float* cW2    = (const float*)d_in[21];
    const float* cb2    = (const float*)d_in[22];
    const float* cW3    = (const float*)d_in[23];
    const float* cb3    = (const float*)d_in[24];
    const float* cW4    = (const float*)d_in[25];
    const float* cb4    = (const float*)d_in[26];
    const float* nig    = (const float*)d_in[27];
    const float* nib    = (const float*)d_in[28];
    const float* nsg    = (const float*)d_in[29];
    const float* nsb    = (const float*)d_in[30];

    char* w = (char*)d_ws;
    auto take = [&](size_t bytes) -> char* {
        char* p = w;
        w += (bytes + 255) & ~(size_t)255;
        return p;
    };

    float* slots   = (float*)take((size_t)524288 * 4);
    short* xbf     = (short*)take((size_t)32768 * 256 * 2);
    short* Wqbf    = (short*)take((size_t)2048 * 2048 * 2);
    short* Wkbf    = (short*)take((size_t)256 * 2048 * 2);
    short* Wvbf    = (short*)take((size_t)256 * 2048 * 2);
    short* gWihbf  = (short*)take((size_t)16 * 384 * 128 * 2);
    short* gWhhbf  = (short*)take((size_t)16 * 384 * 128 * 2);
    short* cvecbf  = (short*)take((size_t)1024 * 128 * 2);
    float* M1f     = (float*)take((size_t)256 * 2048 * 4);
    short* M1bf    = (short*)take((size_t)256 * 2048 * 2);
    short* WvGTbf  = (short*)take((size_t)16 * 384 * 256 * 2);
    float* b1g     = (float*)take((size_t)6144 * 4);
    float* c1      = (float*)take((size_t)256 * 4);
    short* mW1T    = (short*)take((size_t)16 * 128 * 128 * 2);
    short* mW2T    = (short*)take((size_t)16 * 128 * 128 * 2);
    short* cW1T    = (short*)take((size_t)512 * 128 * 2);
    short* cW2T    = (short*)take((size_t)512 * 512 * 2);
    short* cW3T    = (short*)take((size_t)512 * 512 * 2);
    short* cW4T    = (short*)take((size_t)128 * 512 * 2);
    short* hA      = (short*)take((size_t)1024 * 512 * 2);
    short* hB      = (short*)take((size_t)1024 * 512 * 2);
    float* h4      = (float*)take((size_t)1024 * 128 * 4);
    short* s_ln    = (short*)take((size_t)256 * 2048 * 2);
    short* slotsbf = (short*)take((size_t)256 * 2048 * 2);
    float* kqf     = (float*)take((size_t)256 * 256 * 4);
    float* dots    = (float*)take((size_t)32 * 1024 * 8 * 4);
    float* up      = (float*)take((size_t)256 * 256 * 4);
    float* gi      = (float*)take((size_t)256 * 6144 * 4);
    float* gh      = (float*)take((size_t)256 * 6144 * 4);

    float* out_slots = (float*)d_out;
    float* out_attn  = (float*)d_out + 524288;

    // --- prep: converts, transposes, folded weights ------------------------
    cvt_all_k<<<29184, 256, 0, stream>>>(Wq, Wk, Wv, gWih, gWhh, cvec,
                                         Wqbf, Wkbf, Wvbf, gWihbf, gWhhbf, cvecbf, M1f);
    transpose_all_k<<<1152, 256, 0, stream>>>(mW1, mW2, cW1, cW2, cW3, cW4,
                                              mW1T, mW2T, cW1T, cW2T, cW3T, cW4T);
    gemm_bt<3,0,0,0,0,4><<<dim3(4, 32, 4), 256, 0, stream>>>(
        Wkbf, 2048, 0, Wqbf, 2048, 0, M1f, 2048, 0, nullptr, 0, 256, 2048, 2048, 1.f);
    cvt_m1_k<<<512, 256, 0, stream>>>(M1f, M1bf);
    gemm_bt<1,0,0,0,0,1><<<dim3(6, 4, 16), 256, 0, stream>>>(
        gWihbf, 128, 49152, Wvbf, 2048, 128, WvGTbf, 256, 98304, nullptr, 0, 384, 256, 128, 1.f);
    b1c1_k<<<280, 256, 0, stream>>>(bq, Wk, bv, gWih, c1, b1g);

    ln_in_k<<<8192, 256, 0, stream>>>(inputs, nig, nib, xbf);

    // --- concept memory (iteration-invariant) ------------------------------
    gemm_bt<1,1,1,0,0,1><<<dim3(16, 8, 1), 256, 0, stream>>>(cvecbf, 128, 0, cW1T, 128, 0, hA, 512, 0, cb1, 0, 1024, 512, 128, 1.f);
    gemm_bt<1,1,1,0,0,1><<<dim3(16, 8, 1), 256, 0, stream>>>(hA, 512, 0, cW2T, 512, 0, hB, 512, 0, cb2, 0, 1024, 512, 512, 1.f);
    gemm_bt<1,1,1,0,0,1><<<dim3(16, 8, 1), 256, 0, stream>>>(hB, 512, 0, cW3T, 512, 0, hA, 512, 0, cb3, 0, 1024, 512, 512, 1.f);
    gemm_bt<0,0,1,0,0,1><<<dim3(16, 2, 1), 256, 0, stream>>>(hA, 512, 0, cW4T, 512, 0, h4, 128, 0, cb4, 0, 1024, 128, 512, 1.f);

    for (int it = 0; it < 3; ++it) {
        if (it == 0)
            ln_slots_k<1><<<256, 256, 0, stream>>>(slots, noise, smu, sls, nsg, nsb, s_ln, slotsbf, kqf);
        else
            ln_slots_k<0><<<256, 256, 0, stream>>>(slots, noise, smu, sls, nsg, nsb, s_ln, slotsbf, kqf);
        // kq[bs,i] = s_ln @ M1T^T + c1   (split-K=8, f32 atomic)
        gemm_bt<3,0,1,0,0,8><<<dim3(4, 4, 8), 256, 0, stream>>>(
            s_ln, 2048, 0, M1bf, 2048, 0, kqf, 256, 0, c1, 0, 256, 256, 2048, 1.f);
        // dots[b,n,s] = scale * x[b] @ kq[b]^T
        gemm_bt<0,0,0,0,1,1><<<dim3(16, 1, 32), 256, 0, stream>>>(
            xbf, 256, 262144, kqf, 256, 2048, dots, 8, 8192, nullptr, 0, 1024, 8, 256, 0.022097086912079608f);
        // fused softmax + u'
        if (it == 2)
            smup_k<1><<<dim3(8, 32), 256, 0, stream>>>(dots, xbf, up, out_attn);
        else
            smup_k<0><<<dim3(8, 32), 256, 0, stream>>>(dots, xbf, up, out_attn);
        // gi and gh in one launch
        gemm_gigh<<<dim3(4, 6, 32), 256, 0, stream>>>(up, WvGTbf, b1g, slotsbf, gWhhbf, gi, gh);
        // fused: GRU + residual block-MLP + BWA (+ direct out write last iter)
        if (it == 2)
            resid_bwa_k<1><<<dim3(16, 32), 512, 0, stream>>>(slots, gi, gh, gbih, gbhh,
                                                             h4, mW1T, mW2T, mb1, mb2, out_slots);
        else
            resid_bwa_k<0><<<dim3(16, 32), 512, 0, stream>>>(slots, gi, gh, gbih, gbhh,
                                                             h4, mW1T, mW2T, mb1, mb2, out_slots);
    }
}

// Round 7
// 464.729 us; speedup vs baseline: 1.1900x; 1.1244x over previous
//
#include <hip/hip_runtime.h>

typedef __attribute__((ext_vector_type(8))) short short8;
typedef __attribute__((ext_vector_type(4))) float f32x4;

#define DEV static __device__ __forceinline__

DEV float bfs2f(short s) {
    union { unsigned int u; float f; } c;
    c.u = ((unsigned int)(unsigned short)s) << 16;
    return c.f;
}
DEV short f2bfs(float f) {
    union { float f; unsigned int u; } c;
    c.f = f;
    unsigned int u = c.u;
    return (short)((u + 0x7fffu + ((u >> 16) & 1u)) >> 16);  // RNE
}
DEV int imin(int a, int b) { return a < b ? a : b; }
DEV float sigm(float x) { return 1.f / (1.f + expf(-x)); }

// ---------------------------------------------------------------------------
// Fused f32->bf16 convert of all plain weights + zero of M1f (one launch).
// ---------------------------------------------------------------------------
__global__ __launch_bounds__(256) void cvt_all_k(
    const float* __restrict__ Wq, const float* __restrict__ Wk, const float* __restrict__ Wv,
    const float* __restrict__ gih, const float* __restrict__ ghh, const float* __restrict__ cv,
    short* __restrict__ dWq, short* __restrict__ dWk, short* __restrict__ dWv,
    short* __restrict__ dgih, short* __restrict__ dghh, short* __restrict__ dcv,
    float* __restrict__ M1f)
{
    long i = (long)blockIdx.x * 256 + threadIdx.x;
    const float* s; short* d; long o;
    if      (i < 4194304) { s = Wq;  d = dWq;  o = i; }
    else if (i < 4718592) { s = Wk;  d = dWk;  o = i - 4194304; }
    else if (i < 5242880) { s = Wv;  d = dWv;  o = i - 4718592; }
    else if (i < 6029312) { s = gih; d = dgih; o = i - 5242880; }
    else if (i < 6815744) { s = ghh; d = dghh; o = i - 6029312; }
    else if (i < 6946816) { s = cv;  d = dcv;  o = i - 6815744; }
    else if (i < 7471104) { M1f[i - 6946816] = 0.f; return; }
    else return;
    d[o] = f2bfs(s[o]);
}

// ---------------------------------------------------------------------------
// All weight transposes (f32 [R,C] -> bf16 [C,R]) in ONE launch.
// ---------------------------------------------------------------------------
__global__ __launch_bounds__(256) void transpose_all_k(
    const float* __restrict__ mW1, const float* __restrict__ mW2,
    const float* __restrict__ cW1, const float* __restrict__ cW2,
    const float* __restrict__ cW3, const float* __restrict__ cW4,
    short* __restrict__ mW1T, short* __restrict__ mW2T,
    short* __restrict__ cW1T, short* __restrict__ cW2T,
    short* __restrict__ cW3T, short* __restrict__ cW4T)
{
    int id = blockIdx.x;
    const float* in; short* out; int R, C, tx, ty;
    if (id < 256)       { int z = id >> 4, t = id & 15; in = mW1 + z * 16384; out = mW1T + z * 16384; R = 128; C = 128; tx = t & 3;  ty = t >> 2; }
    else if (id < 512)  { id -= 256; int z = id >> 4, t = id & 15; in = mW2 + z * 16384; out = mW2T + z * 16384; R = 128; C = 128; tx = t & 3;  ty = t >> 2; }
    else if (id < 576)  { id -= 512;  in = cW1; out = cW1T; R = 128; C = 512; tx = id & 15; ty = id >> 4; }
    else if (id < 832)  { id -= 576;  in = cW2; out = cW2T; R = 512; C = 512; tx = id & 15; ty = id >> 4; }
    else if (id < 1088) { id -= 832;  in = cW3; out = cW3T; R = 512; C = 512; tx = id & 15; ty = id >> 4; }
    else                { id -= 1088; in = cW4; out = cW4T; R = 512; C = 128; tx = id & 3;  ty = id >> 2; }
    __shared__ short t[32][33];
    int c0 = tx * 32, r0 = ty * 32;
    int x = threadIdx.x & 31, y = threadIdx.x >> 5;
    #pragma unroll
    for (int k = 0; k < 32; k += 8) t[y + k][x] = f2bfs(in[(long)(r0 + y + k) * C + (c0 + x)]);
    __syncthreads();
    #pragma unroll
    for (int k = 0; k < 32; k += 8) out[(long)(c0 + y + k) * R + (r0 + x)] = t[x][y + k];
}

// bf16 transpose per b: xbf [b,1024,256] -> xbfT [b,256,1024]  (prep, once)
__global__ __launch_bounds__(256) void xt_k(const short* __restrict__ in,
                                            short* __restrict__ out)
{
    int b = blockIdx.z;
    int i0 = blockIdx.x * 32, n0 = blockIdx.y * 32;
    __shared__ short tl[32][33];
    int x = threadIdx.x & 31, y = threadIdx.x >> 5;
    const short* ip = in + (long)b * 262144;
    short* op = out + (long)b * 262144;
    #pragma unroll
    for (int k = 0; k < 32; k += 8) tl[y + k][x] = ip[(long)(n0 + y + k) * 256 + i0 + x];
    __syncthreads();
    #pragma unroll
    for (int k = 0; k < 32; k += 8) op[(long)(i0 + y + k) * 1024 + n0 + x] = tl[x][y + k];
}

// ---------------------------------------------------------------------------
// Merged folded-bias prep: c1 and b1g
// ---------------------------------------------------------------------------
__global__ __launch_bounds__(256) void b1c1_k(const float* __restrict__ bq,
                                              const float* __restrict__ Wk,
                                              const float* __restrict__ bv,
                                              const float* __restrict__ gWih,
                                              float* __restrict__ c1,
                                              float* __restrict__ b1g)
{
    int bid = blockIdx.x, tid = threadIdx.x;
    __shared__ float red[4];
    if (bid < 256) {
        const float* row = Wk + (long)bid * 2048;
        float acc = 0.f;
        for (int d = tid; d < 2048; d += 256) acc += bq[d] * row[d];
        #pragma unroll
        for (int d = 1; d < 64; d <<= 1) acc += __shfl_xor(acc, d);
        int w = tid >> 6;
        if ((tid & 63) == 0) red[w] = acc;
        __syncthreads();
        if (tid == 0) c1[bid] = red[0] + red[1] + red[2] + red[3];
    } else {
        int t = (bid - 256) * 256 + tid;   // < 6144
        int nb = t / 384, g = t % 384;
        const float* wrow = gWih + (long)nb * 49152 + (long)g * 128;
        const float* bp = bv + nb * 128;
        float acc = 0.f;
        for (int j = 0; j < 128; j++) acc += bp[j] * wrow[j];
        b1g[t] = acc;
    }
}

// M1f (f32, 524288) -> M1bf (bf16)
__global__ __launch_bounds__(256) void cvt_m1_k(const float* __restrict__ in,
                                                short* __restrict__ out)
{
    int i = (blockIdx.x * 256 + threadIdx.x) * 4;
    f32x4 v = *(const f32x4*)(in + i);
    out[i]     = f2bfs(v[0]);
    out[i + 1] = f2bfs(v[1]);
    out[i + 2] = f2bfs(v[2]);
    out[i + 3] = f2bfs(v[3]);
}

// ---------------------------------------------------------------------------
// Tiled MFMA GEMM core (verified r3 body as device fn).
// ---------------------------------------------------------------------------
template<int OUT_MODE, int RELU, int HAS_BIAS, int A_F32, int B_F32>
DEV void gemm_core(const void* __restrict__ Av, long lda, long abase,
                   const void* __restrict__ Btv, long ldb, long bbase,
                   void* __restrict__ Cv, long ldc, long cbase,
                   const float* __restrict__ bias, long biasbase, int addbias,
                   int M, int N, int K, float scale, int kbeg, int kend,
                   short* As, short* Bs)
{
    const int tid  = threadIdx.x;
    const int wave = tid >> 6, lane = tid & 63;
    const int quad = lane >> 4, l16 = lane & 15;
    const int wr = (wave >> 1) * 32, wc = (wave & 1) * 32;
    const int m0 = blockIdx.x * 64, n0 = blockIdx.y * 64;

    f32x4 acc[2][2] = {};

    const int lrow = tid >> 2;
    const int lk   = (tid & 3) * 8;
    const int arow = imin(m0 + lrow, M - 1);
    const int brow = imin(n0 + lrow, N - 1);
    short* asd = &As[lrow * 40 + lk];
    short* bsd = &Bs[lrow * 40 + lk];

    short8 arS = {}, brS = {};
    f32x4 arF0 = {}, arF1 = {}, brF0 = {}, brF1 = {};

    auto loadA = [&](int k0) {
        if (A_F32) {
            const float* p = (const float*)Av + abase + (long)arow * lda + lk + k0;
            arF0 = *(const f32x4*)p; arF1 = *(const f32x4*)(p + 4);
        } else {
            arS = *(const short8*)((const short*)Av + abase + (long)arow * lda + lk + k0);
        }
    };
    auto loadB = [&](int k0) {
        if (B_F32) {
            const float* p = (const float*)Btv + bbase + (long)brow * ldb + lk + k0;
            brF0 = *(const f32x4*)p; brF1 = *(const f32x4*)(p + 4);
        } else {
            brS = *(const short8*)((const short*)Btv + bbase + (long)brow * ldb + lk + k0);
        }
    };
    auto stage = [&]() {
        if (A_F32) {
            short8 t;
            #pragma unroll
            for (int j = 0; j < 4; j++) { t[j] = f2bfs(arF0[j]); t[j + 4] = f2bfs(arF1[j]); }
            *(short8*)asd = t;
        } else *(short8*)asd = arS;
        if (B_F32) {
            short8 t;
            #pragma unroll
            for (int j = 0; j < 4; j++) { t[j] = f2bfs(brF0[j]); t[j + 4] = f2bfs(brF1[j]); }
            *(short8*)bsd = t;
        } else *(short8*)bsd = brS;
    };

    loadA(kbeg); loadB(kbeg);
    for (int k0 = kbeg; k0 < kend; k0 += 32) {
        stage();
        __syncthreads();
        if (k0 + 32 < kend) { loadA(k0 + 32); loadB(k0 + 32); }
        short8 a0 = *(const short8*)&As[(wr + l16) * 40 + quad * 8];
        short8 a1 = *(const short8*)&As[(wr + 16 + l16) * 40 + quad * 8];
        short8 b0 = *(const short8*)&Bs[(wc + l16) * 40 + quad * 8];
        short8 b1 = *(const short8*)&Bs[(wc + 16 + l16) * 40 + quad * 8];
        acc[0][0] = __builtin_amdgcn_mfma_f32_16x16x32_bf16(a0, b0, acc[0][0], 0, 0, 0);
        acc[0][1] = __builtin_amdgcn_mfma_f32_16x16x32_bf16(a0, b1, acc[0][1], 0, 0, 0);
        acc[1][0] = __builtin_amdgcn_mfma_f32_16x16x32_bf16(a1, b0, acc[1][0], 0, 0, 0);
        acc[1][1] = __builtin_amdgcn_mfma_f32_16x16x32_bf16(a1, b1, acc[1][1], 0, 0, 0);
        __syncthreads();
    }

    #pragma unroll
    for (int sr = 0; sr < 2; sr++) {
        #pragma unroll
        for (int sc = 0; sc < 2; sc++) {
            int gc = n0 + wc + sc * 16 + l16;
            if (gc >= N) continue;
            float bvv = 0.f;
            if (HAS_BIAS && addbias) bvv = bias[biasbase + gc];
            #pragma unroll
            for (int r = 0; r < 4; r++) {
                int gr = m0 + wr + sr * 16 + quad * 4 + r;
                if (gr >= M) continue;
                float v = acc[sr][sc][r] * scale + bvv;
                if (RELU) v = fmaxf(v, 0.f);
                long cidx = cbase + (long)gr * ldc + gc;
                if (OUT_MODE == 0)      ((float*)Cv)[cidx] = v;
                else if (OUT_MODE == 1) ((short*)Cv)[cidx] = f2bfs(v);
                else if (OUT_MODE == 2) ((float*)Cv)[cidx] += v;
                else                    atomicAdd((float*)Cv + cidx, v);
            }
        }
    }
}

template<int OUT_MODE, int RELU, int HAS_BIAS, int A_F32, int B_F32, int SPLITK>
__global__ __launch_bounds__(256) void gemm_bt(
    const void* __restrict__ Av, long lda, long aoff,
    const void* __restrict__ Btv, long ldb, long boff,
    void* __restrict__ Cv, long ldc, long coff,
    const float* __restrict__ bias, long biasoff,
    int M, int N, int K, float scale)
{
    __shared__ __align__(16) short As[64 * 40];
    __shared__ __align__(16) short Bs[64 * 40];
    const int bz = blockIdx.z;
    long abase, bbase, cbase, biasbase;
    int kbeg, kend, addbias;
    if (SPLITK > 1) {
        int ks = K / SPLITK;
        kbeg = bz * ks; kend = kbeg + ks;
        abase = 0; bbase = 0; cbase = 0; biasbase = 0; addbias = (bz == 0);
    } else {
        kbeg = 0; kend = K;
        abase = (long)bz * aoff; bbase = (long)bz * boff; cbase = (long)bz * coff;
        biasbase = (long)bz * biasoff; addbias = 1;
    }
    gemm_core<OUT_MODE, RELU, HAS_BIAS, A_F32, B_F32>(
        Av, lda, abase, Btv, ldb, bbase, Cv, ldc, cbase,
        bias, biasbase, addbias, M, N, K, scale, kbeg, kend, As, Bs);
}

// gi = up @ WvGT + b1g  (z<16)  and  gh = slotsbf @ gWhh  (z>=16), one launch.
__global__ __launch_bounds__(256) void gemm_gigh(
    const float* __restrict__ up, const short* __restrict__ WvGT,
    const float* __restrict__ b1g,
    const short* __restrict__ slotsbf, const short* __restrict__ gWhh,
    float* __restrict__ gi, float* __restrict__ gh)
{
    __shared__ __align__(16) short As[64 * 40];
    __shared__ __align__(16) short Bs[64 * 40];
    int z = blockIdx.z;
    if (z < 16) {
        long nb = z;
        gemm_core<0, 0, 1, 1, 0>(up, 256, 0, WvGT, 256, nb * 98304,
                                 gi, 6144, nb * 384, b1g, nb * 384, 1,
                                 256, 384, 256, 1.f, 0, 256, As, Bs);
    } else {
        long nb = z - 16;
        gemm_core<0, 0, 0, 0, 0>(slotsbf, 2048, nb * 128, gWhh, 128, nb * 49152,
                                 gh, 6144, nb * 384, nullptr, 0, 1,
                                 256, 384, 128, 1.f, 0, 128, As, Bs);
    }
}

// ---------------------------------------------------------------------------
// LN of inputs over INF=256, affine -> bf16. One wave per row.
// ---------------------------------------------------------------------------
__global__ __launch_bounds__(256) void ln_in_k(const float* __restrict__ in,
                                               const float* __restrict__ g,
                                               const float* __restrict__ b,
                                               short* __restrict__ out)
{
    int row  = blockIdx.x * 4 + (threadIdx.x >> 6);
    int lane = threadIdx.x & 63;
    long off = (long)row * 256 + lane * 4;
    f32x4 v4 = *(const f32x4*)(in + off);
    float v[4] = {v4[0], v4[1], v4[2], v4[3]};
    float s = v[0] + v[1] + v[2] + v[3];
    #pragma unroll
    for (int d = 1; d < 64; d <<= 1) s += __shfl_xor(s, d);
    float mean = s * (1.f / 256.f);
    float sq = 0.f;
    #pragma unroll
    for (int k = 0; k < 4; k++) { float dd = v[k] - mean; sq += dd * dd; }
    #pragma unroll
    for (int d = 1; d < 64; d <<= 1) sq += __shfl_xor(sq, d);
    float inv = rsqrtf(sq * (1.f / 256.f) + 1e-5f);
    short* op = out + off;
    #pragma unroll
    for (int k = 0; k < 4; k++)
        op[k] = f2bfs((v[k] - mean) * inv * g[lane * 4 + k] + b[lane * 4 + k]);
}

// ---------------------------------------------------------------------------
// LN of slots over 2048 -> s_ln bf16; raw slots -> bf16; zero kqf. Block/row.
// ---------------------------------------------------------------------------
template<int INIT>
__global__ __launch_bounds__(256) void ln_slots_k(float* __restrict__ slots,
                                                  const float* __restrict__ noise,
                                                  const float* __restrict__ mu,
                                                  const float* __restrict__ ls,
                                                  const float* __restrict__ g,
                                                  const float* __restrict__ b,
                                                  short* __restrict__ s_ln,
                                                  short* __restrict__ slotsbf,
                                                  float* __restrict__ kqf)
{
    int row = blockIdx.x, tid = threadIdx.x;
    kqf[row * 256 + tid] = 0.f;  // pre-zero for split-K atomic kq GEMM
    long base = (long)row * 2048 + tid * 8;
    float v[8];
    if (INIT) {
        #pragma unroll
        for (int k = 0; k < 8; k++) {
            int d = tid * 8 + k;
            v[k] = mu[d] + expf(ls[d]) * noise[base + k];
            slots[base + k] = v[k];
        }
    } else {
        *(f32x4*)&v[0] = *(const f32x4*)(slots + base);
        *(f32x4*)&v[4] = *(const f32x4*)(slots + base + 4);
    }
    float s = 0.f;
    #pragma unroll
    for (int k = 0; k < 8; k++) s += v[k];
    #pragma unroll
    for (int d = 1; d < 64; d <<= 1) s += __shfl_xor(s, d);
    __shared__ float wsum[4], wsq[4];
    int w = tid >> 6, lane = tid & 63;
    if (lane == 0) wsum[w] = s;
    __syncthreads();
    float mean = (wsum[0] + wsum[1] + wsum[2] + wsum[3]) * (1.f / 2048.f);
    float sq = 0.f;
    #pragma unroll
    for (int k = 0; k < 8; k++) { float dd = v[k] - mean; sq += dd * dd; }
    #pragma unroll
    for (int d = 1; d < 64; d <<= 1) sq += __shfl_xor(sq, d);
    if (lane == 0) wsq[w] = sq;
    __syncthreads();
    float var = (wsq[0] + wsq[1] + wsq[2] + wsq[3]) * (1.f / 2048.f);
    float inv = rsqrtf(var + 1e-5f);
    #pragma unroll
    for (int k = 0; k < 8; k++) {
        float xn = (v[k] - mean) * inv;
        s_ln[base + k]     = f2bfs(xn * g[tid * 8 + k] + b[tid * 8 + k]);
        slotsbf[base + k] = f2bfs(v[k]);
    }
}

// ---------------------------------------------------------------------------
// softmax over n (+EPS renorm) per (s,b), 256 threads.
// Writes attnT[b][s][n] (f32, contiguous) for the up-GEMM.
// WRITE_ATTN: also writes the [b,n,s] layout into d_out attn region (last it).
// ---------------------------------------------------------------------------
template<int WRITE_ATTN>
__global__ __launch_bounds__(256) void softmax_k(const float* __restrict__ dots,
                                                 float* __restrict__ attnT,
                                                 float* __restrict__ attng)
{
    int s = blockIdx.x, b = blockIdx.y, tid = threadIdx.x;
    int w = tid >> 6, lane = tid & 63;
    __shared__ float red[8];

    const float* dp = dots + (long)b * 8192 + s;
    float v[4];
    float mx = -1e30f;
    #pragma unroll
    for (int j = 0; j < 4; j++) { v[j] = dp[(tid + j * 256) * 8]; mx = fmaxf(mx, v[j]); }
    #pragma unroll
    for (int d = 1; d < 64; d <<= 1) mx = fmaxf(mx, __shfl_xor(mx, d));
    if (lane == 0) red[w] = mx;
    __syncthreads();
    mx = fmaxf(fmaxf(red[0], red[1]), fmaxf(red[2], red[3]));
    float sum = 0.f;
    #pragma unroll
    for (int j = 0; j < 4; j++) { v[j] = expf(v[j] - mx); sum += v[j]; }
    #pragma unroll
    for (int d = 1; d < 64; d <<= 1) sum += __shfl_xor(sum, d);
    if (lane == 0) red[4 + w] = sum;
    __syncthreads();
    sum = red[4] + red[5] + red[6] + red[7];
    float inv = 1.f / sum;
    float sum2 = 0.f;
    #pragma unroll
    for (int j = 0; j < 4; j++) { v[j] = v[j] * inv + 1e-8f; sum2 += v[j]; }
    #pragma unroll
    for (int d = 1; d < 64; d <<= 1) sum2 += __shfl_xor(sum2, d);
    if (lane == 0) red[w] = sum2;
    __syncthreads();
    float inv2 = 1.f / (red[0] + red[1] + red[2] + red[3]);
    float* at = attnT + (long)b * 8192 + s * 1024;
    #pragma unroll
    for (int j = 0; j < 4; j++) {
        float a = v[j] * inv2;
        int n = tid + j * 256;
        at[n] = a;
        if (WRITE_ATTN) attng[(long)b * 8192 + n * 8 + s] = a;
    }
}

// ---------------------------------------------------------------------------
// FUSED per-(nb,b) tail: GRU -> residual block-MLP -> BWA (verified r3 version)
// WRITE_OUT: also write final slots into d_out slots region (last iteration).
// ---------------------------------------------------------------------------
template<int WRITE_OUT>
__global__ __launch_bounds__(512) void resid_bwa_k(
    float* __restrict__ slots,
    const float* __restrict__ gi, const float* __restrict__ gh,
    const float* __restrict__ bih, const float* __restrict__ bhh,
    const float* __restrict__ h4,
    const short* __restrict__ mW1T, const short* __restrict__ mW2T,
    const float* __restrict__ mb1, const float* __restrict__ mb2,
    float* __restrict__ outp)
{
    int nb = blockIdx.x, b = blockIdx.y, tid = threadIdx.x;
    int lane = tid & 63, r = tid >> 6;

    __shared__ __align__(16) float ml[64 * 132];
    __shared__ __align__(16) short wlds[8192];
    __shared__ __align__(16) float t1[8 * 128];
    __shared__ __align__(16) float t2[8 * 128];
    __shared__ __align__(16) float sc[8 * 64];

    {
        int p = tid >> 3, t8 = tid & 7;
        const float* src = h4 + (long)(p * 16 + nb) * 128 + t8 * 16;
        f32x4 a0 = *(const f32x4*)src;
        f32x4 a1 = *(const f32x4*)(src + 4);
        f32x4 a2 = *(const f32x4*)(src + 8);
        f32x4 a3 = *(const f32x4*)(src + 12);
        float s = 0.f, sq = 0.f;
        #pragma unroll
        for (int k = 0; k < 4; k++) {
            s  += a0[k] + a1[k] + a2[k] + a3[k];
            sq += a0[k]*a0[k] + a1[k]*a1[k] + a2[k]*a2[k] + a3[k]*a3[k];
        }
        #pragma unroll
        for (int d = 1; d < 8; d <<= 1) { s += __shfl_xor(s, d); sq += __shfl_xor(sq, d); }
        float mean = s * (1.f / 128.f);
        float var = sq * (1.f / 128.f) - mean * mean;
        float inv = rsqrtf(var + 1e-5f);
        float* dst = &ml[p * 132 + t8 * 16];
        #pragma unroll
        for (int k = 0; k < 4; k++) {
            dst[k]      = (a0[k] - mean) * inv;
            dst[4 + k]  = (a1[k] - mean) * inv;
            dst[8 + k]  = (a2[k] - mean) * inv;
            dst[12 + k] = (a3[k] - mean) * inv;
        }
    }

    auto stagew = [&](const short* Wh) {
        #pragma unroll
        for (int pass = 0; pass < 2; pass++) {
            int idx = pass * 4096 + tid * 8;
            short8 v = *(const short8*)(Wh + idx);
            int o = idx >> 7;
            int c = (idx >> 3) & 15;
            int key = (o & 15) ^ ((o >> 4) & 3);
            *(short8*)&wlds[o * 128 + ((c ^ key) << 3)] = v;
        }
    };
    stagew(mW1T + (long)nb * 16384);

    int row = b * 8 + r;
    long grow = (long)row * 6144 + nb * 384;
    long srow = (long)row * 2048 + nb * 128;
    int bb = nb * 384;
    float sv0, sv1;
    {
        float ir0 = gi[grow + lane]       + bih[bb + lane];
        float ir1 = gi[grow + lane + 64]  + bih[bb + lane + 64];
        float iz0 = gi[grow + 128 + lane] + bih[bb + 128 + lane];
        float iz1 = gi[grow + 192 + lane] + bih[bb + 192 + lane];
        float in0 = gi[grow + 256 + lane] + bih[bb + 256 + lane];
        float in1 = gi[grow + 320 + lane] + bih[bb + 320 + lane];
        float hr0 = gh[grow + lane]       + bhh[bb + lane];
        float hr1 = gh[grow + lane + 64]  + bhh[bb + lane + 64];
        float hz0 = gh[grow + 128 + lane] + bhh[bb + 128 + lane];
        float hz1 = gh[grow + 192 + lane] + bhh[bb + 192 + lane];
        float hn0 = gh[grow + 256 + lane] + bhh[bb + 256 + lane];
        float hn1 = gh[grow + 320 + lane] + bhh[bb + 320 + lane];
        float h0 = slots[srow + lane], h1 = slots[srow + lane + 64];
        float rg0 = sigm(ir0 + hr0), rg1 = sigm(ir1 + hr1);
        float zg0 = sigm(iz0 + hz0), zg1 = sigm(iz1 + hz1);
        sv0 = (1.f - zg0) * tanhf(in0 + rg0 * hn0) + zg0 * h0;
        sv1 = (1.f - zg1) * tanhf(in1 + rg1 * hn1) + zg1 * h1;
        float s = sv0 + sv1, sq = sv0 * sv0 + sv1 * sv1;
        #pragma unroll
        for (int d = 1; d < 64; d <<= 1) { s += __shfl_xor(s, d); sq += __shfl_xor(sq, d); }
        float mean = s * (1.f / 128.f);
        float var = sq * (1.f / 128.f) - mean * mean;
        float inv = rsqrtf(var + 1e-5f);
        t1[r * 128 + lane]      = (sv0 - mean) * inv;
        t1[r * 128 + lane + 64] = (sv1 - mean) * inv;
    }
    __syncthreads();

    auto mlpdot = [&](const float* xr) -> float {
        int key = (lane & 15) ^ ((lane >> 4) & 3);
        const short* wrow = &wlds[lane * 128];
        float acc0 = 0.f, acc1 = 0.f;
        #pragma unroll
        for (int c = 0; c < 16; c++) {
            f32x4 x0 = *(const f32x4*)(xr + c * 8);
            f32x4 x1 = *(const f32x4*)(xr + c * 8 + 4);
            short8 w = *(const short8*)(wrow + ((c ^ key) << 3));
            acc0 += x0[0]*bfs2f(w[0]) + x0[1]*bfs2f(w[1]) + x0[2]*bfs2f(w[2]) + x0[3]*bfs2f(w[3]);
            acc1 += x1[0]*bfs2f(w[4]) + x1[1]*bfs2f(w[5]) + x1[2]*bfs2f(w[6]) + x1[3]*bfs2f(w[7]);
        }
        return acc0 + acc1;
    };

    float c0 = mlpdot(&t1[r * 128]);
    __syncthreads();
    stagew(mW1T + (long)nb * 16384 + 8192);
    __syncthreads();
    float c1v = mlpdot(&t1[r * 128]);
    t2[r * 128 + lane]      = fmaxf(c0 + mb1[nb * 128 + lane], 0.f);
    t2[r * 128 + lane + 64] = fmaxf(c1v + mb1[nb * 128 + lane + 64], 0.f);
    __syncthreads();
    stagew(mW2T + (long)nb * 16384);
    __syncthreads();

    float y0 = mlpdot(&t2[r * 128]);
    __syncthreads();
    stagew(mW2T + (long)nb * 16384 + 8192);
    __syncthreads();
    float y1 = mlpdot(&t2[r * 128]);
    {
        y0 += mb2[nb * 128 + lane]      + sv0;
        y1 += mb2[nb * 128 + lane + 64] + sv1;
        float s = y0 + y1, sq = y0 * y0 + y1 * y1;
        #pragma unroll
        for (int d = 1; d < 64; d <<= 1) { s += __shfl_xor(s, d); sq += __shfl_xor(sq, d); }
        float mean = s * (1.f / 128.f);
        float var = sq * (1.f / 128.f) - mean * mean;
        float inv = rsqrtf(var + 1e-5f) * 0.08838834764831845f;
        t1[r * 128 + lane]      = (y0 - mean) * inv;
        t1[r * 128 + lane + 64] = (y1 - mean) * inv;
    }
    __syncthreads();

    {
        const float* qr = &t1[r * 128];
        const float* mr = &ml[lane * 132];
        float acc0 = 0.f, acc1 = 0.f;
        #pragma unroll
        for (int j = 0; j < 128; j += 8) {
            f32x4 q0 = *(const f32x4*)(qr + j);
            f32x4 q1 = *(const f32x4*)(qr + j + 4);
            f32x4 m0 = *(const f32x4*)(mr + j);
            f32x4 m1 = *(const f32x4*)(mr + j + 4);
            acc0 += q0[0]*m0[0] + q0[1]*m0[1] + q0[2]*m0[2] + q0[3]*m0[3];
            acc1 += q1[0]*m1[0] + q1[1]*m1[1] + q1[2]*m1[2] + q1[3]*m1[3];
        }
        float acc = acc0 + acc1;
        float mx = acc;
        #pragma unroll
        for (int d = 1; d < 64; d <<= 1) mx = fmaxf(mx, __shfl_xor(mx, d));
        float e = expf(acc - mx);
        float ss = e;
        #pragma unroll
        for (int d = 1; d < 64; d <<= 1) ss += __shfl_xor(ss, d);
        sc[r * 64 + lane] = e / ss;
    }
    __syncthreads();

    {
        const float* scr = &sc[r * 64];
        float a0 = 0.f, a1 = 0.f;
        #pragma unroll 4
        for (int p = 0; p < 64; p++) {
            float a = scr[p];
            a0 += a * ml[p * 132 + lane];
            a1 += a * ml[p * 132 + 64 + lane];
        }
        float* dst = slots + srow;
        dst[lane] = a0; dst[lane + 64] = a1;
        if (WRITE_OUT) {
            outp[srow + lane] = a0; outp[srow + lane + 64] = a1;
        }
    }
}

// ===========================================================================
extern "C" void kernel_launch(void* const* d_in, const int* in_sizes, int n_in,
                              void* d_out, int out_size, void* d_ws, size_t ws_size,
                              hipStream_t stream)
{
    (void)in_sizes; (void)n_in; (void)out_size; (void)ws_size;
    const float* inputs = (const float*)d_in[0];
    const float* noise  = (const float*)d_in[1];
    const float* smu    = (const float*)d_in[2];
    const float* sls    = (const float*)d_in[3];
    const float* Wq     = (const float*)d_in[4];
    const float* bq     = (const float*)d_in[5];
    const float* Wk     = (const float*)d_in[6];
    /* d_in[7] = bk: softmax(axis=n)-invariant; dropped */
    const float* Wv     = (const float*)d_in[8];
    const float* bv     = (const float*)d_in[9];
    const float* gWih   = (const float*)d_in[10];
    const float* gWhh   = (const float*)d_in[11];
    const float* gbih   = (const float*)d_in[12];
    const float* gbhh   = (const float*)d_in[13];
    const float* mW1    = (const float*)d_in[14];
    const float* mb1    = (const float*)d_in[15];
    const float* mW2    = (const float*)d_in[16];
    const float* mb2    = (const float*)d_in[17];
    const float* cvec   = (const float*)d_in[18];
    const float* cW1    = (const float*)d_in[19];
    const float* cb1    = (const float*)d_in[20];
    const float* cW2    = (const float*)d_in[21];
    const float* cb2    = (const float*)d_in[22];
    const float* cW3    = (const float*)d_in[23];
    const float* cb3    = (const float*)d_in[24];
    const float* cW4    = (const float*)d_in[25];
    const float* cb4    = (const float*)d_in[26];
    const float* nig    = (const float*)d_in[27];
    const float* nib    = (const float*)d_in[28];
    const float* nsg    = (const float*)d_in[29];
    const float* nsb    = (const float*)d_in[30];

    char* w = (char*)d_ws;
    auto take = [&](size_t bytes) -> char* {
        char* p = w;
        w += (bytes + 255) & ~(size_t)255;
        return p;
    };

    float* slots   = (float*)take((size_t)524288 * 4);
    short* xbf     = (short*)take((size_t)32768 * 256 * 2);
    short* xbfT    = (short*)take((size_t)32 * 256 * 1024 * 2);
    short* Wqbf    = (short*)take((size_t)2048 * 2048 * 2);
    short* Wkbf    = (short*)take((size_t)256 * 2048 * 2);
    short* Wvbf    = (short*)take((size_t)256 * 2048 * 2);
    short* gWihbf  = (short*)take((size_t)16 * 384 * 128 * 2);
    short* gWhhbf  = (short*)take((size_t)16 * 384 * 128 * 2);
    short* cvecbf  = (short*)take((size_t)1024 * 128 * 2);
    float* M1f     = (float*)take((size_t)256 * 2048 * 4);
    short* M1bf    = (short*)take((size_t)256 * 2048 * 2);
    short* WvGTbf  = (short*)take((size_t)16 * 384 * 256 * 2);
    float* b1g     = (float*)take((size_t)6144 * 4);
    float* c1      = (float*)take((size_t)256 * 4);
    short* mW1T    = (short*)take((size_t)16 * 128 * 128 * 2);
    short* mW2T    = (short*)take((size_t)16 * 128 * 128 * 2);
    short* cW1T    = (short*)take((size_t)512 * 128 * 2);
    short* cW2T    = (short*)take((size_t)512 * 512 * 2);
    short* cW3T    = (short*)take((size_t)512 * 512 * 2);
    short* cW4T    = (short*)take((size_t)128 * 512 * 2);
    short* hA      = (short*)take((size_t)1024 * 512 * 2);
    short* hB      = (short*)take((size_t)1024 * 512 * 2);
    float* h4      = (float*)take((size_t)1024 * 128 * 4);
    short* s_ln    = (short*)take((size_t)256 * 2048 * 2);
    short* slotsbf = (short*)take((size_t)256 * 2048 * 2);
    float* kqf     = (float*)take((size_t)256 * 256 * 4);
    float* dots    = (float*)take((size_t)32 * 1024 * 8 * 4);
    float* attnT   = (float*)take((size_t)32 * 8 * 1024 * 4);
    float* up      = (float*)take((size_t)256 * 256 * 4);
    float* gi      = (float*)take((size_t)256 * 6144 * 4);
    float* gh      = (float*)take((size_t)256 * 6144 * 4);

    float* out_slots = (float*)d_out;
    float* out_attn  = (float*)d_out + 524288;

    // --- prep: converts, transposes, folded weights ------------------------
    cvt_all_k<<<29184, 256, 0, stream>>>(Wq, Wk, Wv, gWih, gWhh, cvec,
                                         Wqbf, Wkbf, Wvbf, gWihbf, gWhhbf, cvecbf, M1f);
    transpose_all_k<<<1152, 256, 0, stream>>>(mW1, mW2, cW1, cW2, cW3, cW4,
                                              mW1T, mW2T, cW1T, cW2T, cW3T, cW4T);
    gemm_bt<3,0,0,0,0,4><<<dim3(4, 32, 4), 256, 0, stream>>>(
        Wkbf, 2048, 0, Wqbf, 2048, 0, M1f, 2048, 0, nullptr, 0, 256, 2048, 2048, 1.f);
    cvt_m1_k<<<512, 256, 0, stream>>>(M1f, M1bf);
    gemm_bt<1,0,0,0,0,1><<<dim3(6, 4, 16), 256, 0, stream>>>(
        gWihbf, 128, 49152, Wvbf, 2048, 128, WvGTbf, 256, 98304, nullptr, 0, 384, 256, 128, 1.f);
    b1c1_k<<<280, 256, 0, stream>>>(bq, Wk, bv, gWih, c1, b1g);

    ln_in_k<<<8192, 256, 0, stream>>>(inputs, nig, nib, xbf);
    xt_k<<<dim3(8, 32, 32), 256, 0, stream>>>(xbf, xbfT);

    // --- concept memory (iteration-invariant) ------------------------------
    gemm_bt<1,1,1,0,0,1><<<dim3(16, 8, 1), 256, 0, stream>>>(cvecbf, 128, 0, cW1T, 128, 0, hA, 512, 0, cb1, 0, 1024, 512, 128, 1.f);
    gemm_bt<1,1,1,0,0,1><<<dim3(16, 8, 1), 256, 0, stream>>>(hA, 512, 0, cW2T, 512, 0, hB, 512, 0, cb2, 0, 1024, 512, 512, 1.f);
    gemm_bt<1,1,1,0,0,1><<<dim3(16, 8, 1), 256, 0, stream>>>(hB, 512, 0, cW3T, 512, 0, hA, 512, 0, cb3, 0, 1024, 512, 512, 1.f);
    gemm_bt<0,0,1,0,0,1><<<dim3(16, 2, 1), 256, 0, stream>>>(hA, 512, 0, cW4T, 512, 0, h4, 128, 0, cb4, 0, 1024, 128, 512, 1.f);

    for (int it = 0; it < 3; ++it) {
        if (it == 0)
            ln_slots_k<1><<<256, 256, 0, stream>>>(slots, noise, smu, sls, nsg, nsb, s_ln, slotsbf, kqf);
        else
            ln_slots_k<0><<<256, 256, 0, stream>>>(slots, noise, smu, sls, nsg, nsb, s_ln, slotsbf, kqf);
        // kq[bs,i] = s_ln @ M1T^T + c1   (split-K=8, f32 atomic)
        gemm_bt<3,0,1,0,0,8><<<dim3(4, 4, 8), 256, 0, stream>>>(
            s_ln, 2048, 0, M1bf, 2048, 0, kqf, 256, 0, c1, 0, 256, 256, 2048, 1.f);
        // dots[b,n,s] = scale * x[b] @ kq[b]^T
        gemm_bt<0,0,0,0,1,1><<<dim3(16, 1, 32), 256, 0, stream>>>(
            xbf, 256, 262144, kqf, 256, 2048, dots, 8, 8192, nullptr, 0, 1024, 8, 256, 0.022097086912079608f);
        // softmax (+EPS renorm) -> attnT [b][s][n]
        if (it == 2)
            softmax_k<1><<<dim3(8, 32), 256, 0, stream>>>(dots, attnT, out_attn);
        else
            softmax_k<0><<<dim3(8, 32), 256, 0, stream>>>(dots, attnT, out_attn);
        // up[b] = attnT[b] @ xbfT[b]^T  (MFMA, distinct x-chunks per block)
        gemm_bt<0,0,0,1,0,1><<<dim3(1, 4, 32), 256, 0, stream>>>(
            attnT, 1024, 8192, xbfT, 1024, 262144, up, 256, 2048, nullptr, 0, 8, 256, 1024, 1.f);
        // gi and gh in one launch
        gemm_gigh<<<dim3(4, 6, 32), 256, 0, stream>>>(up, WvGTbf, b1g, slotsbf, gWhhbf, gi, gh);
        // fused: GRU + residual block-MLP + BWA (+ direct out write last iter)
        if (it == 2)
            resid_bwa_k<1><<<dim3(16, 32), 512, 0, stream>>>(slots, gi, gh, gbih, gbhh,
                                                             h4, mW1T, mW2T, mb1, mb2, out_slots);
        else
            resid_bwa_k<0><<<dim3(16, 32), 512, 0, stream>>>(slots, gi, gh, gbih, gbhh,
                                                             h4, mW1T, mW2T, mb1, mb2, out_slots);
    }
}

// Round 8
// 427.432 us; speedup vs baseline: 1.2939x; 1.0873x over previous
//
#include <hip/hip_runtime.h>

typedef __attribute__((ext_vector_type(8))) short short8;
typedef __attribute__((ext_vector_type(4))) float f32x4;

#define DEV static __device__ __forceinline__

DEV float bfs2f(short s) {
    union { unsigned int u; float f; } c;
    c.u = ((unsigned int)(unsigned short)s) << 16;
    return c.f;
}
DEV short f2bfs(float f) {
    union { float f; unsigned int u; } c;
    c.f = f;
    unsigned int u = c.u;
    return (short)((u + 0x7fffu + ((u >> 16) & 1u)) >> 16);  // RNE
}
DEV int imin(int a, int b) { return a < b ? a : b; }
DEV float sigm(float x) { return 1.f / (1.f + expf(-x)); }

// ---------------------------------------------------------------------------
// Fused f32->bf16 convert of all plain weights + LN of inputs (one launch).
// blocks [0,27136): elementwise converts; [27136,35328): ln_in rows.
// ---------------------------------------------------------------------------
__global__ __launch_bounds__(256) void cvt_ln_k(
    const float* __restrict__ Wq, const float* __restrict__ Wk, const float* __restrict__ Wv,
    const float* __restrict__ gih, const float* __restrict__ ghh, const float* __restrict__ cv,
    short* __restrict__ dWq, short* __restrict__ dWk, short* __restrict__ dWv,
    short* __restrict__ dgih, short* __restrict__ dghh, short* __restrict__ dcv,
    const float* __restrict__ inputs, const float* __restrict__ nig,
    const float* __restrict__ nib, short* __restrict__ xbf)
{
    if (blockIdx.x >= 27136) {
        // ln_in: LN over INF=256, affine -> bf16. One wave per row.
        int row  = (blockIdx.x - 27136) * 4 + (threadIdx.x >> 6);
        int lane = threadIdx.x & 63;
        long off = (long)row * 256 + lane * 4;
        f32x4 v4 = *(const f32x4*)(inputs + off);
        float v[4] = {v4[0], v4[1], v4[2], v4[3]};
        float s = v[0] + v[1] + v[2] + v[3];
        #pragma unroll
        for (int d = 1; d < 64; d <<= 1) s += __shfl_xor(s, d);
        float mean = s * (1.f / 256.f);
        float sq = 0.f;
        #pragma unroll
        for (int k = 0; k < 4; k++) { float dd = v[k] - mean; sq += dd * dd; }
        #pragma unroll
        for (int d = 1; d < 64; d <<= 1) sq += __shfl_xor(sq, d);
        float inv = rsqrtf(sq * (1.f / 256.f) + 1e-5f);
        short* op = xbf + off;
        #pragma unroll
        for (int k = 0; k < 4; k++)
            op[k] = f2bfs((v[k] - mean) * inv * nig[lane * 4 + k] + nib[lane * 4 + k]);
        return;
    }
    long i = (long)blockIdx.x * 256 + threadIdx.x;
    const float* s; short* d; long o;
    if      (i < 4194304) { s = Wq;  d = dWq;  o = i; }
    else if (i < 4718592) { s = Wk;  d = dWk;  o = i - 4194304; }
    else if (i < 5242880) { s = Wv;  d = dWv;  o = i - 4718592; }
    else if (i < 6029312) { s = gih; d = dgih; o = i - 5242880; }
    else if (i < 6815744) { s = ghh; d = dghh; o = i - 6029312; }
    else if (i < 6946816) { s = cv;  d = dcv;  o = i - 6815744; }
    else return;
    d[o] = f2bfs(s[o]);
}

// ---------------------------------------------------------------------------
// All weight transposes (f32 [R,C] -> bf16 [C,R]) + b1c1 folded-bias prep.
// blocks [0,1152): transposes; [1152,1432): c1 / b1g.
// ---------------------------------------------------------------------------
__global__ __launch_bounds__(256) void transpose_b1c1_k(
    const float* __restrict__ mW1, const float* __restrict__ mW2,
    const float* __restrict__ cW1, const float* __restrict__ cW2,
    const float* __restrict__ cW3, const float* __restrict__ cW4,
    short* __restrict__ mW1T, short* __restrict__ mW2T,
    short* __restrict__ cW1T, short* __restrict__ cW2T,
    short* __restrict__ cW3T, short* __restrict__ cW4T,
    const float* __restrict__ bq, const float* __restrict__ Wk,
    const float* __restrict__ bv, const float* __restrict__ gWih,
    float* __restrict__ c1, float* __restrict__ b1g)
{
    int id = blockIdx.x, tid = threadIdx.x;
    if (id >= 1152) {
        int bid = id - 1152;
        __shared__ float red[4];
        if (bid < 256) {
            const float* row = Wk + (long)bid * 2048;
            float acc = 0.f;
            for (int d = tid; d < 2048; d += 256) acc += bq[d] * row[d];
            #pragma unroll
            for (int d = 1; d < 64; d <<= 1) acc += __shfl_xor(acc, d);
            int w = tid >> 6;
            if ((tid & 63) == 0) red[w] = acc;
            __syncthreads();
            if (tid == 0) c1[bid] = red[0] + red[1] + red[2] + red[3];
        } else {
            int t = (bid - 256) * 256 + tid;   // < 6144
            int nb = t / 384, g = t % 384;
            const float* wrow = gWih + (long)nb * 49152 + (long)g * 128;
            const float* bp = bv + nb * 128;
            float acc = 0.f;
            for (int j = 0; j < 128; j++) acc += bp[j] * wrow[j];
            b1g[t] = acc;
        }
        return;
    }
    const float* in; short* out; int R, C, tx, ty;
    if (id < 256)       { int z = id >> 4, t = id & 15; in = mW1 + z * 16384; out = mW1T + z * 16384; R = 128; C = 128; tx = t & 3;  ty = t >> 2; }
    else if (id < 512)  { id -= 256; int z = id >> 4, t = id & 15; in = mW2 + z * 16384; out = mW2T + z * 16384; R = 128; C = 128; tx = t & 3;  ty = t >> 2; }
    else if (id < 576)  { id -= 512;  in = cW1; out = cW1T; R = 128; C = 512; tx = id & 15; ty = id >> 4; }
    else if (id < 832)  { id -= 576;  in = cW2; out = cW2T; R = 512; C = 512; tx = id & 15; ty = id >> 4; }
    else if (id < 1088) { id -= 832;  in = cW3; out = cW3T; R = 512; C = 512; tx = id & 15; ty = id >> 4; }
    else                { id -= 1088; in = cW4; out = cW4T; R = 512; C = 128; tx = id & 3;  ty = id >> 2; }
    __shared__ short t[32][33];
    int c0 = tx * 32, r0 = ty * 32;
    int x = threadIdx.x & 31, y = threadIdx.x >> 5;
    #pragma unroll
    for (int k = 0; k < 32; k += 8) t[y + k][x] = f2bfs(in[(long)(r0 + y + k) * C + (c0 + x)]);
    __syncthreads();
    #pragma unroll
    for (int k = 0; k < 32; k += 8) out[(long)(c0 + y + k) * R + (r0 + x)] = t[x][y + k];
}

// bf16 transpose per b: xbf [b,1024,256] -> xbfT [b,256,1024]  (prep, once)
__global__ __launch_bounds__(256) void xt_k(const short* __restrict__ in,
                                            short* __restrict__ out)
{
    int b = blockIdx.z;
    int i0 = blockIdx.x * 32, n0 = blockIdx.y * 32;
    __shared__ short tl[32][33];
    int x = threadIdx.x & 31, y = threadIdx.x >> 5;
    const short* ip = in + (long)b * 262144;
    short* op = out + (long)b * 262144;
    #pragma unroll
    for (int k = 0; k < 32; k += 8) tl[y + k][x] = ip[(long)(n0 + y + k) * 256 + i0 + x];
    __syncthreads();
    #pragma unroll
    for (int k = 0; k < 32; k += 8) op[(long)(i0 + y + k) * 1024 + n0 + x] = tl[x][y + k];
}

// ---------------------------------------------------------------------------
// Tiled MFMA GEMM core (verified r3 body as device fn).
// ---------------------------------------------------------------------------
template<int OUT_MODE, int RELU, int HAS_BIAS, int A_F32, int B_F32>
DEV void gemm_core(const void* __restrict__ Av, long lda, long abase,
                   const void* __restrict__ Btv, long ldb, long bbase,
                   void* __restrict__ Cv, long ldc, long cbase,
                   const float* __restrict__ bias, long biasbase, int addbias,
                   int M, int N, int K, float scale, int kbeg, int kend,
                   short* As, short* Bs)
{
    const int tid  = threadIdx.x;
    const int wave = tid >> 6, lane = tid & 63;
    const int quad = lane >> 4, l16 = lane & 15;
    const int wr = (wave >> 1) * 32, wc = (wave & 1) * 32;
    const int m0 = blockIdx.x * 64, n0 = blockIdx.y * 64;

    f32x4 acc[2][2] = {};

    const int lrow = tid >> 2;
    const int lk   = (tid & 3) * 8;
    const int arow = imin(m0 + lrow, M - 1);
    const int brow = imin(n0 + lrow, N - 1);
    short* asd = &As[lrow * 40 + lk];
    short* bsd = &Bs[lrow * 40 + lk];

    short8 arS = {}, brS = {};
    f32x4 arF0 = {}, arF1 = {}, brF0 = {}, brF1 = {};

    auto loadA = [&](int k0) {
        if (A_F32) {
            const float* p = (const float*)Av + abase + (long)arow * lda + lk + k0;
            arF0 = *(const f32x4*)p; arF1 = *(const f32x4*)(p + 4);
        } else {
            arS = *(const short8*)((const short*)Av + abase + (long)arow * lda + lk + k0);
        }
    };
    auto loadB = [&](int k0) {
        if (B_F32) {
            const float* p = (const float*)Btv + bbase + (long)brow * ldb + lk + k0;
            brF0 = *(const f32x4*)p; brF1 = *(const f32x4*)(p + 4);
        } else {
            brS = *(const short8*)((const short*)Btv + bbase + (long)brow * ldb + lk + k0);
        }
    };
    auto stage = [&]() {
        if (A_F32) {
            short8 t;
            #pragma unroll
            for (int j = 0; j < 4; j++) { t[j] = f2bfs(arF0[j]); t[j + 4] = f2bfs(arF1[j]); }
            *(short8*)asd = t;
        } else *(short8*)asd = arS;
        if (B_F32) {
            short8 t;
            #pragma unroll
            for (int j = 0; j < 4; j++) { t[j] = f2bfs(brF0[j]); t[j + 4] = f2bfs(brF1[j]); }
            *(short8*)bsd = t;
        } else *(short8*)bsd = brS;
    };

    loadA(kbeg); loadB(kbeg);
    for (int k0 = kbeg; k0 < kend; k0 += 32) {
        stage();
        __syncthreads();
        if (k0 + 32 < kend) { loadA(k0 + 32); loadB(k0 + 32); }
        short8 a0 = *(const short8*)&As[(wr + l16) * 40 + quad * 8];
        short8 a1 = *(const short8*)&As[(wr + 16 + l16) * 40 + quad * 8];
        short8 b0 = *(const short8*)&Bs[(wc + l16) * 40 + quad * 8];
        short8 b1 = *(const short8*)&Bs[(wc + 16 + l16) * 40 + quad * 8];
        acc[0][0] = __builtin_amdgcn_mfma_f32_16x16x32_bf16(a0, b0, acc[0][0], 0, 0, 0);
        acc[0][1] = __builtin_amdgcn_mfma_f32_16x16x32_bf16(a0, b1, acc[0][1], 0, 0, 0);
        acc[1][0] = __builtin_amdgcn_mfma_f32_16x16x32_bf16(a1, b0, acc[1][0], 0, 0, 0);
        acc[1][1] = __builtin_amdgcn_mfma_f32_16x16x32_bf16(a1, b1, acc[1][1], 0, 0, 0);
        __syncthreads();
    }

    #pragma unroll
    for (int sr = 0; sr < 2; sr++) {
        #pragma unroll
        for (int sc = 0; sc < 2; sc++) {
            int gc = n0 + wc + sc * 16 + l16;
            if (gc >= N) continue;
            float bvv = 0.f;
            if (HAS_BIAS && addbias) bvv = bias[biasbase + gc];
            #pragma unroll
            for (int r = 0; r < 4; r++) {
                int gr = m0 + wr + sr * 16 + quad * 4 + r;
                if (gr >= M) continue;
                float v = acc[sr][sc][r] * scale + bvv;
                if (RELU) v = fmaxf(v, 0.f);
                long cidx = cbase + (long)gr * ldc + gc;
                if (OUT_MODE == 0)      ((float*)Cv)[cidx] = v;
                else if (OUT_MODE == 1) ((short*)Cv)[cidx] = f2bfs(v);
                else if (OUT_MODE == 2) ((float*)Cv)[cidx] += v;
                else                    atomicAdd((float*)Cv + cidx, v);
            }
        }
    }
}

template<int OUT_MODE, int RELU, int HAS_BIAS, int A_F32, int B_F32, int SPLITK>
__global__ __launch_bounds__(256) void gemm_bt(
    const void* __restrict__ Av, long lda, long aoff,
    const void* __restrict__ Btv, long ldb, long boff,
    void* __restrict__ Cv, long ldc, long coff,
    const float* __restrict__ bias, long biasoff,
    int M, int N, int K, float scale)
{
    __shared__ __align__(16) short As[64 * 40];
    __shared__ __align__(16) short Bs[64 * 40];
    const int bz = blockIdx.z;
    long abase, bbase, cbase, biasbase;
    int kbeg, kend, addbias;
    if (SPLITK > 1) {
        int ks = K / SPLITK;
        kbeg = bz * ks; kend = kbeg + ks;
        abase = 0; bbase = 0; cbase = 0; biasbase = 0; addbias = (bz == 0);
    } else {
        kbeg = 0; kend = K;
        abase = (long)bz * aoff; bbase = (long)bz * boff; cbase = (long)bz * coff;
        biasbase = (long)bz * biasoff; addbias = 1;
    }
    gemm_core<OUT_MODE, RELU, HAS_BIAS, A_F32, B_F32>(
        Av, lda, abase, Btv, ldb, bbase, Cv, ldc, cbase,
        bias, biasbase, addbias, M, N, K, scale, kbeg, kend, As, Bs);
}

// gi = up @ WvGT + b1g  (z<16)  and  gh = slotsbf @ gWhh  (z>=16), one launch.
__global__ __launch_bounds__(256) void gemm_gigh(
    const float* __restrict__ up, const short* __restrict__ WvGT,
    const float* __restrict__ b1g,
    const short* __restrict__ slotsbf, const short* __restrict__ gWhh,
    float* __restrict__ gi, float* __restrict__ gh)
{
    __shared__ __align__(16) short As[64 * 40];
    __shared__ __align__(16) short Bs[64 * 40];
    int z = blockIdx.z;
    if (z < 16) {
        long nb = z;
        gemm_core<0, 0, 1, 1, 0>(up, 256, 0, WvGT, 256, nb * 98304,
                                 gi, 6144, nb * 384, b1g, nb * 384, 1,
                                 256, 384, 256, 1.f, 0, 256, As, Bs);
    } else {
        long nb = z - 16;
        gemm_core<0, 0, 0, 0, 0>(slotsbf, 2048, nb * 128, gWhh, 128, nb * 49152,
                                 gh, 6144, nb * 384, nullptr, 0, 1,
                                 256, 384, 128, 1.f, 0, 128, As, Bs);
    }
}

// ---------------------------------------------------------------------------
// LN of slots over 2048 -> s_ln bf16; raw slots -> bf16; zero kqf. Block/row.
// ---------------------------------------------------------------------------
template<int INIT>
__global__ __launch_bounds__(256) void ln_slots_k(float* __restrict__ slots,
                                                  const float* __restrict__ noise,
                                                  const float* __restrict__ mu,
                                                  const float* __restrict__ ls,
                                                  const float* __restrict__ g,
                                                  const float* __restrict__ b,
                                                  short* __restrict__ s_ln,
                                                  short* __restrict__ slotsbf,
                                                  float* __restrict__ kqf)
{
    int row = blockIdx.x, tid = threadIdx.x;
    kqf[row * 256 + tid] = 0.f;  // pre-zero for split-K atomic kq GEMM
    long base = (long)row * 2048 + tid * 8;
    float v[8];
    if (INIT) {
        #pragma unroll
        for (int k = 0; k < 8; k++) {
            int d = tid * 8 + k;
            v[k] = mu[d] + expf(ls[d]) * noise[base + k];
            slots[base + k] = v[k];
        }
    } else {
        *(f32x4*)&v[0] = *(const f32x4*)(slots + base);
        *(f32x4*)&v[4] = *(const f32x4*)(slots + base + 4);
    }
    float s = 0.f;
    #pragma unroll
    for (int k = 0; k < 8; k++) s += v[k];
    #pragma unroll
    for (int d = 1; d < 64; d <<= 1) s += __shfl_xor(s, d);
    __shared__ float wsum[4], wsq[4];
    int w = tid >> 6, lane = tid & 63;
    if (lane == 0) wsum[w] = s;
    __syncthreads();
    float mean = (wsum[0] + wsum[1] + wsum[2] + wsum[3]) * (1.f / 2048.f);
    float sq = 0.f;
    #pragma unroll
    for (int k = 0; k < 8; k++) { float dd = v[k] - mean; sq += dd * dd; }
    #pragma unroll
    for (int d = 1; d < 64; d <<= 1) sq += __shfl_xor(sq, d);
    if (lane == 0) wsq[w] = sq;
    __syncthreads();
    float var = (wsq[0] + wsq[1] + wsq[2] + wsq[3]) * (1.f / 2048.f);
    float inv = rsqrtf(var + 1e-5f);
    #pragma unroll
    for (int k = 0; k < 8; k++) {
        float xn = (v[k] - mean) * inv;
        s_ln[base + k]     = f2bfs(xn * g[tid * 8 + k] + b[tid * 8 + k]);
        slotsbf[base + k] = f2bfs(v[k]);
    }
}

// ---------------------------------------------------------------------------
// FUSED softmax + up-GEMM, block (y,b): softmax recomputed per y (cheap, from
// L2-hot dots) -> LDS; MFMA against the block's DISTINCT xbfT slice.
//   up[b][s][i] = sum_n attn[b][s][n] * xbfT[b][i][n],  i in [y*64, y*64+64)
// M=8 via duplicate-row trick (A row = l16&7; rows 8..15 discarded).
// ---------------------------------------------------------------------------
template<int WRITE_ATTN>
__global__ __launch_bounds__(256) void up2_k(const float* __restrict__ dots,
                                             const short* __restrict__ xbfT,
                                             float* __restrict__ up,
                                             float* __restrict__ attng)
{
    int y = blockIdx.x, b = blockIdx.y, tid = threadIdx.x;
    int w = tid >> 6, lane = tid & 63, quad = lane >> 4, l16 = lane & 15;
    __shared__ __align__(16) short attn_l[8][1032];

    // Phase 1: softmax (+EPS renorm) for s = 2w, 2w+1; wave-local.
    #pragma unroll
    for (int sw = 0; sw < 2; sw++) {
        int s = w * 2 + sw;
        const float* dp = dots + (long)b * 8192 + s;
        float v[16];
        float mx = -1e30f;
        #pragma unroll
        for (int k = 0; k < 16; k++) { v[k] = dp[(lane + k * 64) * 8]; mx = fmaxf(mx, v[k]); }
        #pragma unroll
        for (int d = 1; d < 64; d <<= 1) mx = fmaxf(mx, __shfl_xor(mx, d));
        float sum = 0.f;
        #pragma unroll
        for (int k = 0; k < 16; k++) { v[k] = expf(v[k] - mx); sum += v[k]; }
        #pragma unroll
        for (int d = 1; d < 64; d <<= 1) sum += __shfl_xor(sum, d);
        float inv = 1.f / sum;
        float sum2 = 0.f;
        #pragma unroll
        for (int k = 0; k < 16; k++) { v[k] = v[k] * inv + 1e-8f; sum2 += v[k]; }
        #pragma unroll
        for (int d = 1; d < 64; d <<= 1) sum2 += __shfl_xor(sum2, d);
        float inv2 = 1.f / sum2;
        #pragma unroll
        for (int k = 0; k < 16; k++) {
            float a = v[k] * inv2;
            int n = lane + k * 64;
            attn_l[s][n] = f2bfs(a);
            if (WRITE_ATTN && y == 0) attng[(long)b * 8192 + n * 8 + s] = a;
        }
    }
    __syncthreads();

    // Phase 2: MFMA. wave w -> cols c0..c0+15 of this block's 64-col chunk.
    int c0 = y * 64 + w * 16;
    const short* bp = xbfT + (long)b * 262144 + (long)(c0 + l16) * 1024 + quad * 8;
    f32x4 acc = {};
    for (int ks = 0; ks < 32; ks++) {
        short8 a  = *(const short8*)&attn_l[l16 & 7][ks * 32 + quad * 8];
        short8 bb = *(const short8*)(bp + ks * 32);
        acc = __builtin_amdgcn_mfma_f32_16x16x32_bf16(a, bb, acc, 0, 0, 0);
    }
    #pragma unroll
    for (int r = 0; r < 4; r++) {
        int s = quad * 4 + r;
        if (s < 8) up[(long)b * 2048 + s * 256 + c0 + l16] = acc[r];
    }
}

// ---------------------------------------------------------------------------
// FUSED per-(nb,b) tail: GRU -> residual block-MLP -> BWA (verified r3 version)
// WRITE_OUT: also write final slots into d_out slots region (last iteration).
// ---------------------------------------------------------------------------
template<int WRITE_OUT>
__global__ __launch_bounds__(512) void resid_bwa_k(
    float* __restrict__ slots,
    const float* __restrict__ gi, const float* __restrict__ gh,
    const float* __restrict__ bih, const float* __restrict__ bhh,
    const float* __restrict__ h4,
    const short* __restrict__ mW1T, const short* __restrict__ mW2T,
    const float* __restrict__ mb1, const float* __restrict__ mb2,
    float* __restrict__ outp)
{
    int nb = blockIdx.x, b = blockIdx.y, tid = threadIdx.x;
    int lane = tid & 63, r = tid >> 6;

    __shared__ __align__(16) float ml[64 * 132];
    __shared__ __align__(16) short wlds[8192];
    __shared__ __align__(16) float t1[8 * 128];
    __shared__ __align__(16) float t2[8 * 128];
    __shared__ __align__(16) float sc[8 * 64];

    {
        int p = tid >> 3, t8 = tid & 7;
        const float* src = h4 + (long)(p * 16 + nb) * 128 + t8 * 16;
        f32x4 a0 = *(const f32x4*)src;
        f32x4 a1 = *(const f32x4*)(src + 4);
        f32x4 a2 = *(const f32x4*)(src + 8);
        f32x4 a3 = *(const f32x4*)(src + 12);
        float s = 0.f, sq = 0.f;
        #pragma unroll
        for (int k = 0; k < 4; k++) {
            s  += a0[k] + a1[k] + a2[k] + a3[k];
            sq += a0[k]*a0[k] + a1[k]*a1[k] + a2[k]*a2[k] + a3[k]*a3[k];
        }
        #pragma unroll
        for (int d = 1; d < 8; d <<= 1) { s += __shfl_xor(s, d); sq += __shfl_xor(sq, d); }
        float mean = s * (1.f / 128.f);
        float var = sq * (1.f / 128.f) - mean * mean;
        float inv = rsqrtf(var + 1e-5f);
        float* dst = &ml[p * 132 + t8 * 16];
        #pragma unroll
        for (int k = 0; k < 4; k++) {
            dst[k]      = (a0[k] - mean) * inv;
            dst[4 + k]  = (a1[k] - mean) * inv;
            dst[8 + k]  = (a2[k] - mean) * inv;
            dst[12 + k] = (a3[k] - mean) * inv;
        }
    }

    auto stagew = [&](const short* Wh) {
        #pragma unroll
        for (int pass = 0; pass < 2; pass++) {
            int idx = pass * 4096 + tid * 8;
            short8 v = *(const short8*)(Wh + idx);
            int o = idx >> 7;
            int c = (idx >> 3) & 15;
            int key = (o & 15) ^ ((o >> 4) & 3);
            *(short8*)&wlds[o * 128 + ((c ^ key) << 3)] = v;
        }
    };
    stagew(mW1T + (long)nb * 16384);

    int row = b * 8 + r;
    long grow = (long)row * 6144 + nb * 384;
    long srow = (long)row * 2048 + nb * 128;
    int bb = nb * 384;
    float sv0, sv1;
    {
        float ir0 = gi[grow + lane]       + bih[bb + lane];
        float ir1 = gi[grow + lane + 64]  + bih[bb + lane + 64];
        float iz0 = gi[grow + 128 + lane] + bih[bb + 128 + lane];
        float iz1 = gi[grow + 192 + lane] + bih[bb + 192 + lane];
        float in0 = gi[grow + 256 + lane] + bih[bb + 256 + lane];
        float in1 = gi[grow + 320 + lane] + bih[bb + 320 + lane];
        float hr0 = gh[grow + lane]       + bhh[bb + lane];
        float hr1 = gh[grow + lane + 64]  + bhh[bb + lane + 64];
        float hz0 = gh[grow + 128 + lane] + bhh[bb + 128 + lane];
        float hz1 = gh[grow + 192 + lane] + bhh[bb + 192 + lane];
        float hn0 = gh[grow + 256 + lane] + bhh[bb + 256 + lane];
        float hn1 = gh[grow + 320 + lane] + bhh[bb + 320 + lane];
        float h0 = slots[srow + lane], h1 = slots[srow + lane + 64];
        float rg0 = sigm(ir0 + hr0), rg1 = sigm(ir1 + hr1);
        float zg0 = sigm(iz0 + hz0), zg1 = sigm(iz1 + hz1);
        sv0 = (1.f - zg0) * tanhf(in0 + rg0 * hn0) + zg0 * h0;
        sv1 = (1.f - zg1) * tanhf(in1 + rg1 * hn1) + zg1 * h1;
        float s = sv0 + sv1, sq = sv0 * sv0 + sv1 * sv1;
        #pragma unroll
        for (int d = 1; d < 64; d <<= 1) { s += __shfl_xor(s, d); sq += __shfl_xor(sq, d); }
        float mean = s * (1.f / 128.f);
        float var = sq * (1.f / 128.f) - mean * mean;
        float inv = rsqrtf(var + 1e-5f);
        t1[r * 128 + lane]      = (sv0 - mean) * inv;
        t1[r * 128 + lane + 64] = (sv1 - mean) * inv;
    }
    __syncthreads();

    auto mlpdot = [&](const float* xr) -> float {
        int key = (lane & 15) ^ ((lane >> 4) & 3);
        const short* wrow = &wlds[lane * 128];
        float acc0 = 0.f, acc1 = 0.f;
        #pragma unroll
        for (int c = 0; c < 16; c++) {
            f32x4 x0 = *(const f32x4*)(xr + c * 8);
            f32x4 x1 = *(const f32x4*)(xr + c * 8 + 4);
            short8 w = *(const short8*)(wrow + ((c ^ key) << 3));
            acc0 += x0[0]*bfs2f(w[0]) + x0[1]*bfs2f(w[1]) + x0[2]*bfs2f(w[2]) + x0[3]*bfs2f(w[3]);
            acc1 += x1[0]*bfs2f(w[4]) + x1[1]*bfs2f(w[5]) + x1[2]*bfs2f(w[6]) + x1[7 - 7 + 6]*0.f + x1[2]*0.f + x1[3]*bfs2f(w[7]) + x1[2]*bfs2f(w[6]);
        }
        return acc0 + acc1;
    };
    (void)mlpdot;

    auto mlpdot2 = [&](const float* xr) -> float {
        int key = (lane & 15) ^ ((lane >> 4) & 3);
        const short* wrow = &wlds[lane * 128];
        float acc0 = 0.f, acc1 = 0.f;
        #pragma unroll
        for (int c = 0; c < 16; c++) {
            f32x4 x0 = *(const f32x4*)(xr + c * 8);
            f32x4 x1 = *(const f32x4*)(xr + c * 8 + 4);
            short8 w = *(const short8*)(wrow + ((c ^ key) << 3));
            acc0 += x0[0]*bfs2f(w[0]) + x0[1]*bfs2f(w[1]) + x0[2]*bfs2f(w[2]) + x0[3]*bfs2f(w[3]);
            acc1 += x1[0]*bfs2f(w[4]) + x1[1]*bfs2f(w[5]) + x1[2]*bfs2f(w[6]) + x1[3]*bfs2f(w[7]);
        }
        return acc0 + acc1;
    };

    float c0 = mlpdot2(&t1[r * 128]);
    __syncthreads();
    stagew(mW1T + (long)nb * 16384 + 8192);
    __syncthreads();
    float c1v = mlpdot2(&t1[r * 128]);
    t2[r * 128 + lane]      = fmaxf(c0 + mb1[nb * 128 + lane], 0.f);
    t2[r * 128 + lane + 64] = fmaxf(c1v + mb1[nb * 128 + lane + 64], 0.f);
    __syncthreads();
    stagew(mW2T + (long)nb * 16384);
    __syncthreads();

    float y0 = mlpdot2(&t2[r * 128]);
    __syncthreads();
    stagew(mW2T + (long)nb * 16384 + 8192);
    __syncthreads();
    float y1 = mlpdot2(&t2[r * 128]);
    {
        y0 += mb2[nb * 128 + lane]      + sv0;
        y1 += mb2[nb * 128 + lane + 64] + sv1;
        float s = y0 + y1, sq = y0 * y0 + y1 * y1;
        #pragma unroll
        for (int d = 1; d < 64; d <<= 1) { s += __shfl_xor(s, d); sq += __shfl_xor(sq, d); }
        float mean = s * (1.f / 128.f);
        float var = sq * (1.f / 128.f) - mean * mean;
        float inv = rsqrtf(var + 1e-5f) * 0.08838834764831845f;
        t1[r * 128 + lane]      = (y0 - mean) * inv;
        t1[r * 128 + lane + 64] = (y1 - mean) * inv;
    }
    __syncthreads();

    {
        const float* qr = &t1[r * 128];
        const float* mr = &ml[lane * 132];
        float acc0 = 0.f, acc1 = 0.f;
        #pragma unroll
        for (int j = 0; j < 128; j += 8) {
            f32x4 q0 = *(const f32x4*)(qr + j);
            f32x4 q1 = *(const f32x4*)(qr + j + 4);
            f32x4 m0 = *(const f32x4*)(mr + j);
            f32x4 m1 = *(const f32x4*)(mr + j + 4);
            acc0 += q0[0]*m0[0] + q0[1]*m0[1] + q0[2]*m0[2] + q0[3]*m0[3];
            acc1 += q1[0]*m1[0] + q1[1]*m1[1] + q1[2]*m1[2] + q1[3]*m1[3];
        }
        float acc = acc0 + acc1;
        float mx = acc;
        #pragma unroll
        for (int d = 1; d < 64; d <<= 1) mx = fmaxf(mx, __shfl_xor(mx, d));
        float e = expf(acc - mx);
        float ss = e;
        #pragma unroll
        for (int d = 1; d < 64; d <<= 1) ss += __shfl_xor(ss, d);
        sc[r * 64 + lane] = e / ss;
    }
    __syncthreads();

    {
        const float* scr = &sc[r * 64];
        float a0 = 0.f, a1 = 0.f;
        #pragma unroll 4
        for (int p = 0; p < 64; p++) {
            float a = scr[p];
            a0 += a * ml[p * 132 + lane];
            a1 += a * ml[p * 132 + 64 + lane];
        }
        float* dst = slots + srow;
        dst[lane] = a0; dst[lane + 64] = a1;
        if (WRITE_OUT) {
            outp[srow + lane] = a0; outp[srow + lane + 64] = a1;
        }
    }
}

// ===========================================================================
extern "C" void kernel_launch(void* const* d_in, const int* in_sizes, int n_in,
                              void* d_out, int out_size, void* d_ws, size_t ws_size,
                              hipStream_t stream)
{
    (void)in_sizes; (void)n_in; (void)out_size; (void)ws_size;
    const float* inputs = (const float*)d_in[0];
    const float* noise  = (const float*)d_in[1];
    const float* smu    = (const float*)d_in[2];
    const float* sls    = (const float*)d_in[3];
    const float* Wq     = (const float*)d_in[4];
    const float* bq     = (const float*)d_in[5];
    const float* Wk     = (const float*)d_in[6];
    /* d_in[7] = bk: softmax(axis=n)-invariant; dropped */
    const float* Wv     = (const float*)d_in[8];
    const float* bv     = (const float*)d_in[9];
    const float* gWih   = (const float*)d_in[10];
    const float* gWhh   = (const float*)d_in[11];
    const float* gbih   = (const float*)d_in[12];
    const float* gbhh   = (const float*)d_in[13];
    const float* mW1    = (const float*)d_in[14];
    const float* mb1    = (const float*)d_in[15];
    const float* mW2    = (const float*)d_in[16];
    const float* mb2    = (const float*)d_in[17];
    const float* cvec   = (const float*)d_in[18];
    const float* cW1    = (const float*)d_in[19];
    const float* cb1    = (const float*)d_in[20];
    const float* cW2    = (const float*)d_in[21];
    const float* cb2    = (const float*)d_in[22];
    const float* cW3    = (const float*)d_in[23];
    const float* cb3    = (const float*)d_in[24];
    const float* cW4    = (const float*)d_in[25];
    const float* cb4    = (const float*)d_in[26];
    const float* nig    = (const float*)d_in[27];
    const float* nib    = (const float*)d_in[28];
    const float* nsg    = (const float*)d_in[29];
    const float* nsb    = (const float*)d_in[30];

    char* w = (char*)d_ws;
    auto take = [&](size_t bytes) -> char* {
        char* p = w;
        w += (bytes + 255) & ~(size_t)255;
        return p;
    };

    float* slots   = (float*)take((size_t)524288 * 4);
    short* xbf     = (short*)take((size_t)32768 * 256 * 2);
    short* xbfT    = (short*)take((size_t)32 * 256 * 1024 * 2);
    short* Wqbf    = (short*)take((size_t)2048 * 2048 * 2);
    short* Wkbf    = (short*)take((size_t)256 * 2048 * 2);
    short* Wvbf    = (short*)take((size_t)256 * 2048 * 2);
    short* gWihbf  = (short*)take((size_t)16 * 384 * 128 * 2);
    short* gWhhbf  = (short*)take((size_t)16 * 384 * 128 * 2);
    short* cvecbf  = (short*)take((size_t)1024 * 128 * 2);
    short* M1bf    = (short*)take((size_t)256 * 2048 * 2);
    short* WvGTbf  = (short*)take((size_t)16 * 384 * 256 * 2);
    float* b1g     = (float*)take((size_t)6144 * 4);
    float* c1      = (float*)take((size_t)256 * 4);
    short* mW1T    = (short*)take((size_t)16 * 128 * 128 * 2);
    short* mW2T    = (short*)take((size_t)16 * 128 * 128 * 2);
    short* cW1T    = (short*)take((size_t)512 * 128 * 2);
    short* cW2T    = (short*)take((size_t)512 * 512 * 2);
    short* cW3T    = (short*)take((size_t)512 * 512 * 2);
    short* cW4T    = (short*)take((size_t)128 * 512 * 2);
    short* hA      = (short*)take((size_t)1024 * 512 * 2);
    short* hB      = (short*)take((size_t)1024 * 512 * 2);
    float* h4      = (float*)take((size_t)1024 * 128 * 4);
    short* s_ln    = (short*)take((size_t)256 * 2048 * 2);
    short* slotsbf = (short*)take((size_t)256 * 2048 * 2);
    float* kqf     = (float*)take((size_t)256 * 256 * 4);
    float* dots    = (float*)take((size_t)32 * 1024 * 8 * 4);
    float* up      = (float*)take((size_t)256 * 256 * 4);
    float* gi      = (float*)take((size_t)256 * 6144 * 4);
    float* gh      = (float*)take((size_t)256 * 6144 * 4);

    float* out_slots = (float*)d_out;
    float* out_attn  = (float*)d_out + 524288;

    // --- prep: converts + ln_in, transposes + b1c1, folded weights ---------
    cvt_ln_k<<<35328, 256, 0, stream>>>(Wq, Wk, Wv, gWih, gWhh, cvec,
                                        Wqbf, Wkbf, Wvbf, gWihbf, gWhhbf, cvecbf,
                                        inputs, nig, nib, xbf);
    transpose_b1c1_k<<<1432, 256, 0, stream>>>(mW1, mW2, cW1, cW2, cW3, cW4,
                                               mW1T, mW2T, cW1T, cW2T, cW3T, cW4T,
                                               bq, Wk, bv, gWih, c1, b1g);
    // M1bf[i,e] = sum_d Wk[i,d] Wq[e,d]  (direct bf16 store, no split-K)
    gemm_bt<1,0,0,0,0,1><<<dim3(4, 32, 1), 256, 0, stream>>>(
        Wkbf, 2048, 0, Wqbf, 2048, 0, M1bf, 2048, 0, nullptr, 0, 256, 2048, 2048, 1.f);
    gemm_bt<1,0,0,0,0,1><<<dim3(6, 4, 16), 256, 0, stream>>>(
        gWihbf, 128, 49152, Wvbf, 2048, 128, WvGTbf, 256, 98304, nullptr, 0, 384, 256, 128, 1.f);
    xt_k<<<dim3(8, 32, 32), 256, 0, stream>>>(xbf, xbfT);

    // --- concept memory (iteration-invariant) ------------------------------
    gemm_bt<1,1,1,0,0,1><<<dim3(16, 8, 1), 256, 0, stream>>>(cvecbf, 128, 0, cW1T, 128, 0, hA, 512, 0, cb1, 0, 1024, 512, 128, 1.f);
    gemm_bt<1,1,1,0,0,1><<<dim3(16, 8, 1), 256, 0, stream>>>(hA, 512, 0, cW2T, 512, 0, hB, 512, 0, cb2, 0, 1024, 512, 512, 1.f);
    gemm_bt<1,1,1,0,0,1><<<dim3(16, 8, 1), 256, 0, stream>>>(hB, 512, 0, cW3T, 512, 0, hA, 512, 0, cb3, 0, 1024, 512, 512, 1.f);
    gemm_bt<0,0,1,0,0,1><<<dim3(16, 2, 1), 256, 0, stream>>>(hA, 512, 0, cW4T, 512, 0, h4, 128, 0, cb4, 0, 1024, 128, 512, 1.f);

    for (int it = 0; it < 3; ++it) {
        if (it == 0)
            ln_slots_k<1><<<256, 256, 0, stream>>>(slots, noise, smu, sls, nsg, nsb, s_ln, slotsbf, kqf);
        else
            ln_slots_k<0><<<256, 256, 0, stream>>>(slots, noise, smu, sls, nsg, nsb, s_ln, slotsbf, kqf);
        // kq[bs,i] = s_ln @ M1T^T + c1   (split-K=8, f32 atomic)
        gemm_bt<3,0,1,0,0,8><<<dim3(4, 4, 8), 256, 0, stream>>>(
            s_ln, 2048, 0, M1bf, 2048, 0, kqf, 256, 0, c1, 0, 256, 256, 2048, 1.f);
        // dots[b,n,s] = scale * x[b] @ kq[b]^T
        gemm_bt<0,0,0,0,1,1><<<dim3(16, 1, 32), 256, 0, stream>>>(
            xbf, 256, 262144, kqf, 256, 2048, dots, 8, 8192, nullptr, 0, 1024, 8, 256, 0.022097086912079608f);
        // fused softmax + up-GEMM (distinct xbfT slice per block)
        if (it == 2)
            up2_k<1><<<dim3(4, 32), 256, 0, stream>>>(dots, xbfT, up, out_attn);
        else
            up2_k<0><<<dim3(4, 32), 256, 0, stream>>>(dots, xbfT, up, out_attn);
        // gi and gh in one launch
        gemm_gigh<<<dim3(4, 6, 32), 256, 0, stream>>>(up, WvGTbf, b1g, slotsbf, gWhhbf, gi, gh);
        // fused: GRU + residual block-MLP + BWA (+ direct out write last iter)
        if (it == 2)
            resid_bwa_k<1><<<dim3(16, 32), 512, 0, stream>>>(slots, gi, gh, gbih, gbhh,
                                                             h4, mW1T, mW2T, mb1, mb2, out_slots);
        else
            resid_bwa_k<0><<<dim3(16, 32), 512, 0, stream>>>(slots, gi, gh, gbih, gbhh,
                                                             h4, mW1T, mW2T, mb1, mb2, out_slots);
    }
}